// Round 2
// baseline (938.189 us; speedup 1.0000x reference)
//
#include <hip/hip_runtime.h>
#include <cmath>

#define Bn   8
#define Cn   64
#define HWc  65536      // 256*256
#define HPc  246        // 256-11+1
#define HPWPc 60516     // 246*246
#define C1v  0.01f      // (0.01*10)^2
#define C2v  0.09f      // (0.03*10)^2
#define VPITCH 220      // vb5 row pitch (floats): max write 200+19, max read 140+71 -> 220 suffices

// 11-tap normalized gaussian, sigma=1.5 (double, then f32 cast — matches numpy)
static __device__ __forceinline__ void gauss11(float* gw) {
    double gg[11]; double s = 0.0;
#pragma unroll
    for (int j = 0; j < 11; ++j) { double d = (double)(j - 5); gg[j] = exp(-(d * d) / 4.5); s += gg[j]; }
#pragma unroll
    for (int j = 0; j < 11; ++j) gw[j] = (float)(gg[j] / s);
}

static __device__ __forceinline__ float4 f4z() { return make_float4(0.f, 0.f, 0.f, 0.f); }
static __device__ __forceinline__ float4 f4scale(float g, const float4 v) {
    return make_float4(g * v.x, g * v.y, g * v.z, g * v.w);
}
static __device__ __forceinline__ void f4add(float4& a, const float4 v) {
    a.x += v.x; a.y += v.y; a.z += v.z; a.w += v.w;
}
static __device__ __forceinline__ void f4fma(float4& a, const float4 u, const float4 v) {
    a.x = fmaf(u.x, v.x, a.x); a.y = fmaf(u.y, v.y, a.y);
    a.z = fmaf(u.z, v.z, a.z); a.w = fmaf(u.w, v.w, a.w);
}

// wave64 sum via DPP (VALU pipe, no LDS traffic). Result valid in lane 63.
static __device__ __forceinline__ float wave_sum64(float v) {
    v += __int_as_float(__builtin_amdgcn_update_dpp(0, __float_as_int(v), 0x111, 0xf, 0xf, true)); // row_shr:1
    v += __int_as_float(__builtin_amdgcn_update_dpp(0, __float_as_int(v), 0x112, 0xf, 0xf, true)); // row_shr:2
    v += __int_as_float(__builtin_amdgcn_update_dpp(0, __float_as_int(v), 0x114, 0xf, 0xf, true)); // row_shr:4
    v += __int_as_float(__builtin_amdgcn_update_dpp(0, __float_as_int(v), 0x118, 0xf, 0xf, true)); // row_shr:8
    v += __int_as_float(__builtin_amdgcn_update_dpp(0, __float_as_int(v), 0x142, 0xf, 0xf, true)); // row_bcast:15
    v += __int_as_float(__builtin_amdgcn_update_dpp(0, __float_as_int(v), 0x143, 0xf, 0xf, true)); // row_bcast:31
    return v;
}

// K1: channel max/mean/min (-> xcf planes, RAW) + masked stats atomics
__global__ __launch_bounds__(256) void k1_stats(const float* __restrict__ x, const int* __restrict__ mask,
                                                float* __restrict__ xcf, float* __restrict__ stats) {
    const int b = blockIdx.y;
    const int p0 = blockIdx.x * 1024 + threadIdx.x * 4;
    const float4* xp = (const float4*)(x + (size_t)b * Cn * HWc) + (p0 >> 2);
    float4 v = xp[0];
    float4 vmax = v, vmin = v, vsum = v;
#pragma unroll 4
    for (int c = 1; c < Cn; ++c) {
        float4 u = xp[(size_t)c * (HWc / 4)];
        vmax.x = fmaxf(vmax.x, u.x); vmax.y = fmaxf(vmax.y, u.y);
        vmax.z = fmaxf(vmax.z, u.z); vmax.w = fmaxf(vmax.w, u.w);
        vmin.x = fminf(vmin.x, u.x); vmin.y = fminf(vmin.y, u.y);
        vmin.z = fminf(vmin.z, u.z); vmin.w = fminf(vmin.w, u.w);
        vsum.x += u.x; vsum.y += u.y; vsum.z += u.z; vsum.w += u.w;
    }
    float4 vmean = make_float4(vsum.x * (1.f / 64.f), vsum.y * (1.f / 64.f),
                               vsum.z * (1.f / 64.f), vsum.w * (1.f / 64.f));
    *(float4*)(xcf + (size_t)(b * 3 + 0) * HWc + p0) = vmax;
    *(float4*)(xcf + (size_t)(b * 3 + 1) * HWc + p0) = vmean;
    *(float4*)(xcf + (size_t)(b * 3 + 2) * HWc + p0) = vmin;
    int4 mv = *(const int4*)(mask + (size_t)b * HWc + p0);
    float m0 = (float)mv.x, m1 = (float)mv.y, m2 = (float)mv.z, m3 = (float)mv.w;
    float r[7];
    r[0] = m0 + m1 + m2 + m3;
    r[1] = vmax.x * m0 + vmax.y * m1 + vmax.z * m2 + vmax.w * m3;
    r[2] = vmean.x * m0 + vmean.y * m1 + vmean.z * m2 + vmean.w * m3;
    r[3] = vmin.x * m0 + vmin.y * m1 + vmin.z * m2 + vmin.w * m3;
    r[4] = vmax.x * vmax.x * m0 + vmax.y * vmax.y * m1 + vmax.z * vmax.z * m2 + vmax.w * vmax.w * m3;
    r[5] = vmean.x * vmean.x * m0 + vmean.y * vmean.y * m1 + vmean.z * vmean.z * m2 + vmean.w * vmean.w * m3;
    r[6] = vmin.x * vmin.x * m0 + vmin.y * vmin.y * m1 + vmin.z * vmin.z * m2 + vmin.w * vmin.w * m3;
#pragma unroll
    for (int k = 0; k < 7; ++k) {
        float vv = wave_sum64(r[k]);
        if ((threadIdx.x & 63) == 63) atomicAdd(&stats[b * 8 + k], vv);
    }
}

// K4: mu_f = blur(xf), ef2 = blur(xf^2); xf computed inline from raw xc + mask + stats.
__global__ __launch_bounds__(256) void k4_blur3(const float* __restrict__ xc, const int* __restrict__ mask,
                                                const float* __restrict__ stats,
                                                float* __restrict__ muf, float* __restrict__ ef2g) {
    __shared__ __align__(16) float vb2[32 * 92];
    const int t = threadIdx.x;
    const int bi = blockIdx.z, b = bi / 3, i = bi % 3;
    const int y0 = blockIdx.y * 32, x0 = blockIdx.x * 32;
    float gw[11]; gauss11(gw);
    const float nst = stats[b * 8 + 0];
    const float s1 = stats[b * 8 + 1 + i], s2 = stats[b * 8 + 4 + i];
    const float mean = s1 / nst;
    const float rstd = rsqrtf((s2 - s1 * s1 / nst) / (nst - 1.0f));
    if (t < 176) {
        const int rg = t / 11, cg = t % 11, colo = cg * 4;
        const int gcb = min(x0 + colo, 252);
        const float* xp = xc + (size_t)bi * HWc;
        const int* mp = mask + (size_t)b * HWc;
        float4 av0 = f4z(), ab0 = f4z(), av1 = f4z(), ab1 = f4z();
#pragma unroll
        for (int k = 0; k < 12; ++k) {
            int gr = min(y0 + 2 * rg + k, 255);
            float4 v = *(const float4*)(xp + gr * 256 + gcb);
            int4 mv = *(const int4*)(mp + gr * 256 + gcb);
            float4 f;
            f.x = (v.x - mean) * rstd * (float)mv.x;
            f.y = (v.y - mean) * rstd * (float)mv.y;
            f.z = (v.z - mean) * rstd * (float)mv.z;
            f.w = (v.w - mean) * rstd * (float)mv.w;
            if (k <= 10) { float4 tv = f4scale(gw[k], f); f4add(av0, tv); f4fma(ab0, tv, f); }
            if (k >= 1)  { float4 tv = f4scale(gw[k - 1], f); f4add(av1, tv); f4fma(ab1, tv, f); }
        }
        {
            float* dst = &vb2[(2 * rg + 0) * 92 + colo * 2];
            *(float4*)&dst[0] = make_float4(av0.x, ab0.x, av0.y, ab0.y);
            *(float4*)&dst[4] = make_float4(av0.z, ab0.z, av0.w, ab0.w);
        }
        {
            float* dst = &vb2[(2 * rg + 1) * 92 + colo * 2];
            *(float4*)&dst[0] = make_float4(av1.x, ab1.x, av1.y, ab1.y);
            *(float4*)&dst[4] = make_float4(av1.z, ab1.z, av1.w, ab1.w);
        }
    }
    __syncthreads();
    {
        const int erow = t >> 3, ecg = t & 7;
        const int oy = y0 + erow;
        const float* src = &vb2[erow * 92 + ecg * 8];
        float a00 = 0.f, a01 = 0.f, a02 = 0.f, a03 = 0.f;
        float a10 = 0.f, a11 = 0.f, a12 = 0.f, a13 = 0.f;
#pragma unroll
        for (int m = 0; m < 14; ++m) {
            float v0 = src[m * 2 + 0];
            float v1 = src[m * 2 + 1];
#pragma unroll
            for (int j = 0; j < 4; ++j) {
                const int kk = m - j;
                if (kk >= 0 && kk <= 10) {
                    if (j == 0) { a00 = fmaf(gw[kk], v0, a00); a10 = fmaf(gw[kk], v1, a10); }
                    if (j == 1) { a01 = fmaf(gw[kk], v0, a01); a11 = fmaf(gw[kk], v1, a11); }
                    if (j == 2) { a02 = fmaf(gw[kk], v0, a02); a12 = fmaf(gw[kk], v1, a12); }
                    if (j == 3) { a03 = fmaf(gw[kk], v0, a03); a13 = fmaf(gw[kk], v1, a13); }
                }
            }
        }
        if (oy < HPc) {
            size_t ob = (size_t)bi * HPWPc + (size_t)oy * HPc;
            int oxb = x0 + ecg * 4;
            if (oxb + 0 < HPc) { muf[ob + oxb + 0] = a00; ef2g[ob + oxb + 0] = a10; }
            if (oxb + 1 < HPc) { muf[ob + oxb + 1] = a01; ef2g[ob + oxb + 1] = a11; }
            if (oxb + 2 < HPc) { muf[ob + oxb + 2] = a02; ef2g[ob + oxb + 2] = a12; }
            if (oxb + 3 < HPc) { muf[ob + oxb + 3] = a03; ef2g[ob + oxb + 3] = a13; }
        }
    }
}

// ---- K5 macro machinery (no local arrays; minimal persistent registers) ----
#define T(F,J,KK,V) h##F##_##J = fmaf(G##KK, (V), h##F##_##J);
#define TM0(F,V)  T(F,0,0,V)
#define TM1(F,V)  T(F,0,1,V) T(F,1,0,V)
#define TM2(F,V)  T(F,0,2,V) T(F,1,1,V) T(F,2,0,V)
#define TM3(F,V)  T(F,0,3,V) T(F,1,2,V) T(F,2,1,V) T(F,3,0,V)
#define TM4(F,V)  T(F,0,4,V) T(F,1,3,V) T(F,2,2,V) T(F,3,1,V)
#define TM5(F,V)  T(F,0,5,V) T(F,1,4,V) T(F,2,3,V) T(F,3,2,V)
#define TM6(F,V)  T(F,0,6,V) T(F,1,5,V) T(F,2,4,V) T(F,3,3,V)
#define TM7(F,V)  T(F,0,7,V) T(F,1,6,V) T(F,2,5,V) T(F,3,4,V)
#define TM8(F,V)  T(F,0,8,V) T(F,1,7,V) T(F,2,6,V) T(F,3,5,V)
#define TM9(F,V)  T(F,0,9,V) T(F,1,8,V) T(F,2,7,V) T(F,3,6,V)
#define TM10(F,V) T(F,0,10,V) T(F,1,9,V) T(F,2,8,V) T(F,3,7,V)
#define TM11(F,V) T(F,1,10,V) T(F,2,9,V) T(F,3,8,V)
#define TM12(F,V) T(F,2,10,V) T(F,3,9,V)
#define TM13(F,V) T(F,3,10,V)

#define DECLH(J) float h0_##J = 0.f, h1_##J = 0.f, h2_##J = 0.f, h3_##J = 0.f, h4_##J = 0.f;
// persistent per-thread constants: M = mu1, S = (s1 + C2) or +inf (invalid marker)
#define DECLJ(J) float M0_##J, M1_##J, M2_##J, S0_##J, S1_##J, S2_##J;
#define SETI(I,J) { float mu1 = 0.f, e2 = 0.f; \
    if (vld) { size_t o = (size_t)(b * 3 + I) * HPWPc + (size_t)oy * HPc + ox; mu1 = muf[o]; e2 = ef2g[o]; } \
    M##I##_##J = mu1; S##I##_##J = vld ? ((e2 - mu1 * mu1) + C2v) : __builtin_inff(); }
#define SETJ(J) { int ox = ox0 + J; bool vld = (oy < HPc) && (ox < HPc); \
    SETI(0,J) SETI(1,J) SETI(2,J) }

#define SSIMI(I,J,HV) { float am = M##I##_##J * m2; \
    float num = fmaf(2.f, am, C1v) * fmaf(2.f, (HV) - am, C2v); \
    float den = fmaf(M##I##_##J, M##I##_##J, c1m2) * (S##I##_##J + s2); \
    sa##I += num * __builtin_amdgcn_rcpf(den); }
#define SSIMJ(J) { float m2 = h0_##J; float m2sq = m2 * m2; \
    float c1m2 = C1v + m2sq; float s2 = h1_##J - m2sq; \
    SSIMI(0,J,h2_##J) SSIMI(1,J,h3_##J) SSIMI(2,J,h2_##J == h2_##J ? h4_##J : h4_##J) }

#undef SSIMJ
#define SSIMJ(J) { float m2 = h0_##J; float m2sq = m2 * m2; \
    float c1m2 = C1v + m2sq; float s2 = h1_##J - m2sq; \
    SSIMI(0,J,h2_##J) SSIMI(1,J,h3_##J) SSIMI(2,J,h4_##J) }

#define VSTEP(K, DOA, DOB, GA, GB) { \
    int gr = y0 + 2 * vrg + (K); gr = (gr > 255) ? 255 : gr; \
    float4 xv = *(const float4*)(xp + gr * 256 + gcb); \
    const int ro = (2 * vrg + (K)) * 44 + vcolo; \
    float4 f0 = *(const float4*)&f0in[ro]; \
    float4 f1v = *(const float4*)&f1in[ro]; \
    float4 f2v = *(const float4*)&f2in[ro]; \
    if (DOA) { float4 tv = f4scale((GA), xv); f4add(xA0, tv); f4fma(xQ0, tv, xv); \
               f4fma(p00, tv, f0); f4fma(p10, tv, f1v); f4fma(p20, tv, f2v); } \
    if (DOB) { float4 tv = f4scale((GB), xv); f4add(xA1, tv); f4fma(xQ1, tv, xv); \
               f4fma(p01, tv, f0); f4fma(p11, tv, f1v); f4fma(p21, tv, f2v); } }

// K5: per (b, 32x32 tile): xf tiles staged in LDS once; full 64-channel loop.
// __launch_bounds__(256,2): 128-VGPR budget — (256,3) spills (~6.7 GB scratch traffic, R2-R4).
// Double-buffered vb5 (pitch 220): vertical(c+1) writes one buffer while horizontal(c)
// reads the other -> ONE barrier per channel (65 total vs 129). Vertical's 12 global
// b128 loads issue before horizontal's ~150 FMAs, which hide their latency.
// LDS = 3*42*44*4 + 2*32*220*4 = 78,496 B -> 2 blocks/CU (157.7 KB < 160 KB).
// NOTE (R0/R1 post-mortem): SQ_LDS_BANK_CONFLICT ~5.1e7 is the inherent 8-phase cost of
// wave64 b128 LDS ops (1024B @ 128B/clk), NOT fixable conflicts — 8-aligned remap was a no-op.
__global__ __launch_bounds__(256, 2) void k5_main(const float* __restrict__ x, const float* __restrict__ xc,
                                                  const int* __restrict__ mask, const float* __restrict__ stats,
                                                  const float* __restrict__ muf, const float* __restrict__ ef2g,
                                                  float* __restrict__ ssum) {
    __shared__ __align__(16) float f0in[42 * 44];
    __shared__ __align__(16) float f1in[42 * 44];
    __shared__ __align__(16) float f2in[42 * 44];
    __shared__ __align__(16) float vb5a[32 * VPITCH];
    __shared__ __align__(16) float vb5b[32 * VPITCH];
    const int t = threadIdx.x;
    const int b = blockIdx.z;
    const int y0 = blockIdx.y * 32, x0 = blockIdx.x * 32;
    // gauss weights as named scalars (same numerics as gauss11)
    const double e0 = exp(-25.0 / 4.5), e1 = exp(-16.0 / 4.5), e2d = exp(-9.0 / 4.5),
                 e3 = exp(-4.0 / 4.5), e4 = exp(-1.0 / 4.5);
    const double sg = 1.0 + 2.0 * (e0 + e1 + e2d + e3 + e4);
    const float G0 = (float)(e0 / sg), G1 = (float)(e1 / sg), G2 = (float)(e2d / sg),
                G3 = (float)(e3 / sg), G4 = (float)(e4 / sg), G5 = (float)(1.0 / sg);
    const float G6 = G4, G7 = G3, G8 = G2, G9 = G1, G10 = G0;
    // per-(b,i) normalization constants
    const float nst = stats[b * 8 + 0];
    const float s1a = stats[b * 8 + 1], s2a = stats[b * 8 + 4];
    const float s1b = stats[b * 8 + 2], s2b = stats[b * 8 + 5];
    const float s1c = stats[b * 8 + 3], s2c = stats[b * 8 + 6];
    const float mean0 = s1a / nst, rstd0 = rsqrtf((s2a - s1a * s1a / nst) / (nst - 1.0f));
    const float mean1 = s1b / nst, rstd1 = rsqrtf((s2b - s1b * s1b / nst) / (nst - 1.0f));
    const float mean2 = s1c / nst, rstd2 = rsqrtf((s2c - s1c * s1c / nst) / (nst - 1.0f));
    // stage normalized xf tiles (once per block)
    for (int q = t; q < 42 * 11; q += 256) {
        int row = q / 11, cg = q % 11;
        int gr = min(y0 + row, 255), gc = min(x0 + cg * 4, 252);
        int go = gr * 256 + gc;
        int lo = row * 44 + cg * 4;
        int4 mv = *(const int4*)(mask + (size_t)b * HWc + go);
        float m0 = (float)mv.x, m1 = (float)mv.y, m2 = (float)mv.z, m3 = (float)mv.w;
        float4 v0 = *(const float4*)(xc + (size_t)(b * 3 + 0) * HWc + go);
        v0.x = (v0.x - mean0) * rstd0 * m0; v0.y = (v0.y - mean0) * rstd0 * m1;
        v0.z = (v0.z - mean0) * rstd0 * m2; v0.w = (v0.w - mean0) * rstd0 * m3;
        *(float4*)&f0in[lo] = v0;
        float4 v1 = *(const float4*)(xc + (size_t)(b * 3 + 1) * HWc + go);
        v1.x = (v1.x - mean1) * rstd1 * m0; v1.y = (v1.y - mean1) * rstd1 * m1;
        v1.z = (v1.z - mean1) * rstd1 * m2; v1.w = (v1.w - mean1) * rstd1 * m3;
        *(float4*)&f1in[lo] = v1;
        float4 v2 = *(const float4*)(xc + (size_t)(b * 3 + 2) * HWc + go);
        v2.x = (v2.x - mean2) * rstd2 * m0; v2.y = (v2.y - mean2) * rstd2 * m1;
        v2.z = (v2.z - mean2) * rstd2 * m2; v2.w = (v2.w - mean2) * rstd2 * m3;
        *(float4*)&f2in[lo] = v2;
    }
    // per-thread c-independent eval constants (named scalars, 24 persistent regs)
    const int erow = t >> 3, ecg = t & 7;
    const int oy = y0 + erow;
    const int ox0 = x0 + ecg * 4;
    DECLJ(0) DECLJ(1) DECLJ(2) DECLJ(3)
    SETJ(0) SETJ(1) SETJ(2) SETJ(3)
    const float* xb = x + (size_t)b * Cn * HWc;
    const int vrg = t / 11, vcg = t % 11, vcolo = vcg * 4;
    const int gcb = min(x0 + vcolo, 252);
    const bool vact = (t < 176);

    // vertical separable pass for channel c into write-buffer vbW
    auto vert = [&](int c, float* vbW) {
        if (!vact) return;
        const float* xp = xb + (size_t)c * HWc;
        float4 xA0 = f4z(), xQ0 = f4z(), p00 = f4z(), p10 = f4z(), p20 = f4z();
        float4 xA1 = f4z(), xQ1 = f4z(), p01 = f4z(), p11 = f4z(), p21 = f4z();
        VSTEP(0, 1, 0, G0, G0)  VSTEP(1, 1, 1, G1, G0)  VSTEP(2, 1, 1, G2, G1)
        VSTEP(3, 1, 1, G3, G2)  VSTEP(4, 1, 1, G4, G3)  VSTEP(5, 1, 1, G5, G4)
        VSTEP(6, 1, 1, G6, G5)  VSTEP(7, 1, 1, G7, G6)  VSTEP(8, 1, 1, G8, G7)
        VSTEP(9, 1, 1, G9, G8)  VSTEP(10, 1, 1, G10, G9) VSTEP(11, 0, 1, G0, G10)
        {
            float* dst = &vbW[(2 * vrg + 0) * VPITCH + vcolo * 5];
            *(float4*)&dst[0]  = make_float4(xA0.x, xQ0.x, p00.x, p10.x);
            *(float4*)&dst[4]  = make_float4(p20.x, xA0.y, xQ0.y, p00.y);
            *(float4*)&dst[8]  = make_float4(p10.y, p20.y, xA0.z, xQ0.z);
            *(float4*)&dst[12] = make_float4(p00.z, p10.z, p20.z, xA0.w);
            *(float4*)&dst[16] = make_float4(xQ0.w, p00.w, p10.w, p20.w);
        }
        {
            float* dst = &vbW[(2 * vrg + 1) * VPITCH + vcolo * 5];
            *(float4*)&dst[0]  = make_float4(xA1.x, xQ1.x, p01.x, p11.x);
            *(float4*)&dst[4]  = make_float4(p21.x, xA1.y, xQ1.y, p01.y);
            *(float4*)&dst[8]  = make_float4(p11.y, p21.y, xA1.z, xQ1.z);
            *(float4*)&dst[12] = make_float4(p01.z, p11.z, p21.z, xA1.w);
            *(float4*)&dst[16] = make_float4(xQ1.w, p01.w, p11.w, p21.w);
        }
    };

    // horizontal pass + SSIM accumulate for channel c from read-buffer vbR
    auto horiz = [&](int c, const float* vbR) {
        const float* src = &vbR[erow * VPITCH + ecg * 20];
        DECLH(0) DECLH(1) DECLH(2) DECLH(3)
        float4 L0 = *(const float4*)(src + 0);
        TM0(0, L0.x) TM0(1, L0.y) TM0(2, L0.z) TM0(3, L0.w)
        float4 L1 = *(const float4*)(src + 4);
        TM0(4, L1.x) TM1(0, L1.y) TM1(1, L1.z) TM1(2, L1.w)
        float4 L2 = *(const float4*)(src + 8);
        TM1(3, L2.x) TM1(4, L2.y) TM2(0, L2.z) TM2(1, L2.w)
        float4 L3 = *(const float4*)(src + 12);
        TM2(2, L3.x) TM2(3, L3.y) TM2(4, L3.z) TM3(0, L3.w)
        float4 L4 = *(const float4*)(src + 16);
        TM3(1, L4.x) TM3(2, L4.y) TM3(3, L4.z) TM3(4, L4.w)
        float4 L5 = *(const float4*)(src + 20);
        TM4(0, L5.x) TM4(1, L5.y) TM4(2, L5.z) TM4(3, L5.w)
        float4 L6 = *(const float4*)(src + 24);
        TM4(4, L6.x) TM5(0, L6.y) TM5(1, L6.z) TM5(2, L6.w)
        float4 L7 = *(const float4*)(src + 28);
        TM5(3, L7.x) TM5(4, L7.y) TM6(0, L7.z) TM6(1, L7.w)
        float4 L8 = *(const float4*)(src + 32);
        TM6(2, L8.x) TM6(3, L8.y) TM6(4, L8.z) TM7(0, L8.w)
        float4 L9 = *(const float4*)(src + 36);
        TM7(1, L9.x) TM7(2, L9.y) TM7(3, L9.z) TM7(4, L9.w)
        float4 L10 = *(const float4*)(src + 40);
        TM8(0, L10.x) TM8(1, L10.y) TM8(2, L10.z) TM8(3, L10.w)
        float4 L11 = *(const float4*)(src + 44);
        TM8(4, L11.x) TM9(0, L11.y) TM9(1, L11.z) TM9(2, L11.w)
        float4 L12 = *(const float4*)(src + 48);
        TM9(3, L12.x) TM9(4, L12.y) TM10(0, L12.z) TM10(1, L12.w)
        float4 L13 = *(const float4*)(src + 52);
        TM10(2, L13.x) TM10(3, L13.y) TM10(4, L13.z) TM11(0, L13.w)
        float4 L14 = *(const float4*)(src + 56);
        TM11(1, L14.x) TM11(2, L14.y) TM11(3, L14.z) TM11(4, L14.w)
        float4 L15 = *(const float4*)(src + 60);
        TM12(0, L15.x) TM12(1, L15.y) TM12(2, L15.z) TM12(3, L15.w)
        float4 L16 = *(const float4*)(src + 64);
        TM12(4, L16.x) TM13(0, L16.y) TM13(1, L16.z) TM13(2, L16.w)
        float4 L17 = *(const float4*)(src + 68);
        TM13(3, L17.x) TM13(4, L17.y)
        float sa0 = 0.f, sa1 = 0.f, sa2 = 0.f;
        SSIMJ(0) SSIMJ(1) SSIMJ(2) SSIMJ(3)
        sa0 = wave_sum64(sa0);
        sa1 = wave_sum64(sa1);
        sa2 = wave_sum64(sa2);
        if ((t & 63) == 63) {
            atomicAdd(&ssum[(b * 3 + 0) * 64 + c], sa0);
            atomicAdd(&ssum[(b * 3 + 1) * 64 + c], sa1);
            atomicAdd(&ssum[(b * 3 + 2) * 64 + c], sa2);
        }
    };

    __syncthreads();           // f-tiles staged
    vert(0, vb5a);             // prologue: fill buffer A
    for (int c = 0; c < Cn; ++c) {
        __syncthreads();       // vert(c) writes done; horiz(c-1) reads done
        if (c + 1 < Cn) vert(c + 1, (c & 1) ? vb5a : vb5b);
        horiz(c, (c & 1) ? vb5b : vb5a);
    }
}

// K6: normalize ssim sums -> ssim_info output; conv3 over C + MLP head -> h output
__global__ __launch_bounds__(512) void k6_head(const float* __restrict__ ssum, const float* __restrict__ cw,
                                               const float* __restrict__ w1, const float* __restrict__ b1,
                                               const float* __restrict__ w2, const float* __restrict__ b2,
                                               float* __restrict__ out) {
    __shared__ float si[1536];
    __shared__ float h0[512];
    __shared__ float h1[512];
    const int t = threadIdx.x;
    const float inv = 1.0f / (float)HPWPc;
    for (int idx = t; idx < 1536; idx += 512) {
        float v = ssum[idx] * inv;
        si[idx] = v;
        out[512 + idx] = v;
    }
    __syncthreads();
    const int b = t >> 6, y = t & 63;
    float acc = 0.f;
#pragma unroll
    for (int i = 0; i < 3; ++i) {
#pragma unroll
        for (int kh = 0; kh < 3; ++kh) {
            int yy = y + kh - 1;
            if (yy >= 0 && yy < 64) acc = fmaf(si[(b * 3 + i) * 64 + yy], cw[i * 3 + kh], acc);
        }
    }
    h0[t] = fmaxf(acc, 0.f);
    __syncthreads();
    float a1 = b1[y];
    for (int c = 0; c < 64; ++c) a1 = fmaf(h0[(b << 6) + c], w1[(y << 6) + c], a1);
    h1[t] = fmaxf(a1, 0.f);
    __syncthreads();
    float a2 = b2[y];
    for (int c = 0; c < 64; ++c) a2 = fmaf(h1[(b << 6) + c], w2[(y << 6) + c], a2);
    out[t] = 1.f / (1.f + expf(-a2));
}

extern "C" void kernel_launch(void* const* d_in, const int* in_sizes, int n_in,
                              void* d_out, int out_size, void* d_ws, size_t ws_size,
                              hipStream_t stream) {
    const float* x      = (const float*)d_in[0];
    const int*   mask   = (const int*)d_in[1];
    const float* conv_w = (const float*)d_in[2];
    const float* w1     = (const float*)d_in[3];
    const float* b1     = (const float*)d_in[4];
    const float* w2     = (const float*)d_in[5];
    const float* b2     = (const float*)d_in[6];
    float* out = (float*)d_out;

    float* wsf   = (float*)d_ws;
    float* stats = wsf;                       // 64 floats (8 b x 8 slots)
    float* ssum  = wsf + 64;                  // 1536 floats
    float* xcf   = wsf + 1600;                // 8*3*65536 raw xc (max/mean/min)
    float* muf   = xcf + (size_t)Bn * 3 * HWc;      // 8*3*60516
    float* ef2   = muf + (size_t)Bn * 3 * HPWPc;    // 8*3*60516

    hipMemsetAsync(d_ws, 0, 6400, stream);  // stats + ssum accumulators

    k1_stats<<<dim3(64, 8), 256, 0, stream>>>(x, mask, xcf, stats);
    k4_blur3<<<dim3(8, 8, 24), 256, 0, stream>>>(xcf, mask, stats, muf, ef2);
    k5_main<<<dim3(8, 8, 8), 256, 0, stream>>>(x, xcf, mask, stats, muf, ef2, ssum);
    k6_head<<<1, 512, 0, stream>>>(ssum, conv_w, w1, b1, w2, b2, out);
}

// Round 3
// 656.774 us; speedup vs baseline: 1.4285x; 1.4285x over previous
//
#include <hip/hip_runtime.h>
#include <cmath>

#define Bn   8
#define Cn   64
#define HWc  65536      // 256*256
#define HPc  246        // 256-11+1
#define HPWPc 60516     // 246*246
#define C1v  0.01f      // (0.01*10)^2
#define C2v  0.09f      // (0.03*10)^2
#define VPITCH 224      // vb5 row pitch (floats). 224 ≡ 0 mod 32 dwords -> horiz b128 reads
                        // conflict-free; 2 buffers fit: 2*32*224*4 + 22176 = 79520 B < 80 KB.

// 11-tap normalized gaussian, sigma=1.5 (double, then f32 cast — matches numpy)
static __device__ __forceinline__ void gauss11(float* gw) {
    double gg[11]; double s = 0.0;
#pragma unroll
    for (int j = 0; j < 11; ++j) { double d = (double)(j - 5); gg[j] = exp(-(d * d) / 4.5); s += gg[j]; }
#pragma unroll
    for (int j = 0; j < 11; ++j) gw[j] = (float)(gg[j] / s);
}

static __device__ __forceinline__ float4 f4z() { return make_float4(0.f, 0.f, 0.f, 0.f); }
static __device__ __forceinline__ float4 f4scale(float g, const float4 v) {
    return make_float4(g * v.x, g * v.y, g * v.z, g * v.w);
}
static __device__ __forceinline__ void f4add(float4& a, const float4 v) {
    a.x += v.x; a.y += v.y; a.z += v.z; a.w += v.w;
}
static __device__ __forceinline__ void f4fma(float4& a, const float4 u, const float4 v) {
    a.x = fmaf(u.x, v.x, a.x); a.y = fmaf(u.y, v.y, a.y);
    a.z = fmaf(u.z, v.z, a.z); a.w = fmaf(u.w, v.w, a.w);
}

// wave64 sum via DPP (VALU pipe, no LDS traffic). Result valid in lane 63.
static __device__ __forceinline__ float wave_sum64(float v) {
    v += __int_as_float(__builtin_amdgcn_update_dpp(0, __float_as_int(v), 0x111, 0xf, 0xf, true)); // row_shr:1
    v += __int_as_float(__builtin_amdgcn_update_dpp(0, __float_as_int(v), 0x112, 0xf, 0xf, true)); // row_shr:2
    v += __int_as_float(__builtin_amdgcn_update_dpp(0, __float_as_int(v), 0x114, 0xf, 0xf, true)); // row_shr:4
    v += __int_as_float(__builtin_amdgcn_update_dpp(0, __float_as_int(v), 0x118, 0xf, 0xf, true)); // row_shr:8
    v += __int_as_float(__builtin_amdgcn_update_dpp(0, __float_as_int(v), 0x142, 0xf, 0xf, true)); // row_bcast:15
    v += __int_as_float(__builtin_amdgcn_update_dpp(0, __float_as_int(v), 0x143, 0xf, 0xf, true)); // row_bcast:31
    return v;
}

// K1: channel max/mean/min (-> xcf planes, RAW) + masked stats atomics
__global__ __launch_bounds__(256) void k1_stats(const float* __restrict__ x, const int* __restrict__ mask,
                                                float* __restrict__ xcf, float* __restrict__ stats) {
    const int b = blockIdx.y;
    const int p0 = blockIdx.x * 1024 + threadIdx.x * 4;
    const float4* xp = (const float4*)(x + (size_t)b * Cn * HWc) + (p0 >> 2);
    float4 v = xp[0];
    float4 vmax = v, vmin = v, vsum = v;
#pragma unroll 4
    for (int c = 1; c < Cn; ++c) {
        float4 u = xp[(size_t)c * (HWc / 4)];
        vmax.x = fmaxf(vmax.x, u.x); vmax.y = fmaxf(vmax.y, u.y);
        vmax.z = fmaxf(vmax.z, u.z); vmax.w = fmaxf(vmax.w, u.w);
        vmin.x = fminf(vmin.x, u.x); vmin.y = fminf(vmin.y, u.y);
        vmin.z = fminf(vmin.z, u.z); vmin.w = fminf(vmin.w, u.w);
        vsum.x += u.x; vsum.y += u.y; vsum.z += u.z; vsum.w += u.w;
    }
    float4 vmean = make_float4(vsum.x * (1.f / 64.f), vsum.y * (1.f / 64.f),
                               vsum.z * (1.f / 64.f), vsum.w * (1.f / 64.f));
    *(float4*)(xcf + (size_t)(b * 3 + 0) * HWc + p0) = vmax;
    *(float4*)(xcf + (size_t)(b * 3 + 1) * HWc + p0) = vmean;
    *(float4*)(xcf + (size_t)(b * 3 + 2) * HWc + p0) = vmin;
    int4 mv = *(const int4*)(mask + (size_t)b * HWc + p0);
    float m0 = (float)mv.x, m1 = (float)mv.y, m2 = (float)mv.z, m3 = (float)mv.w;
    float r[7];
    r[0] = m0 + m1 + m2 + m3;
    r[1] = vmax.x * m0 + vmax.y * m1 + vmax.z * m2 + vmax.w * m3;
    r[2] = vmean.x * m0 + vmean.y * m1 + vmean.z * m2 + vmean.w * m3;
    r[3] = vmin.x * m0 + vmin.y * m1 + vmin.z * m2 + vmin.w * m3;
    r[4] = vmax.x * vmax.x * m0 + vmax.y * vmax.y * m1 + vmax.z * vmax.z * m2 + vmax.w * vmax.w * m3;
    r[5] = vmean.x * vmean.x * m0 + vmean.y * vmean.y * m1 + vmean.z * vmean.z * m2 + vmean.w * vmean.w * m3;
    r[6] = vmin.x * vmin.x * m0 + vmin.y * vmin.y * m1 + vmin.z * vmin.z * m2 + vmin.w * vmin.w * m3;
#pragma unroll
    for (int k = 0; k < 7; ++k) {
        float vv = wave_sum64(r[k]);
        if ((threadIdx.x & 63) == 63) atomicAdd(&stats[b * 8 + k], vv);
    }
}

// K4: mu_f = blur(xf), ef2 = blur(xf^2); xf computed inline from raw xc + mask + stats.
__global__ __launch_bounds__(256) void k4_blur3(const float* __restrict__ xc, const int* __restrict__ mask,
                                                const float* __restrict__ stats,
                                                float* __restrict__ muf, float* __restrict__ ef2g) {
    __shared__ __align__(16) float vb2[32 * 92];
    const int t = threadIdx.x;
    const int bi = blockIdx.z, b = bi / 3, i = bi % 3;
    const int y0 = blockIdx.y * 32, x0 = blockIdx.x * 32;
    float gw[11]; gauss11(gw);
    const float nst = stats[b * 8 + 0];
    const float s1 = stats[b * 8 + 1 + i], s2 = stats[b * 8 + 4 + i];
    const float mean = s1 / nst;
    const float rstd = rsqrtf((s2 - s1 * s1 / nst) / (nst - 1.0f));
    if (t < 176) {
        const int rg = t / 11, cg = t % 11, colo = cg * 4;
        const int gcb = min(x0 + colo, 252);
        const float* xp = xc + (size_t)bi * HWc;
        const int* mp = mask + (size_t)b * HWc;
        float4 av0 = f4z(), ab0 = f4z(), av1 = f4z(), ab1 = f4z();
#pragma unroll
        for (int k = 0; k < 12; ++k) {
            int gr = min(y0 + 2 * rg + k, 255);
            float4 v = *(const float4*)(xp + gr * 256 + gcb);
            int4 mv = *(const int4*)(mp + gr * 256 + gcb);
            float4 f;
            f.x = (v.x - mean) * rstd * (float)mv.x;
            f.y = (v.y - mean) * rstd * (float)mv.y;
            f.z = (v.z - mean) * rstd * (float)mv.z;
            f.w = (v.w - mean) * rstd * (float)mv.w;
            if (k <= 10) { float4 tv = f4scale(gw[k], f); f4add(av0, tv); f4fma(ab0, tv, f); }
            if (k >= 1)  { float4 tv = f4scale(gw[k - 1], f); f4add(av1, tv); f4fma(ab1, tv, f); }
        }
        {
            float* dst = &vb2[(2 * rg + 0) * 92 + colo * 2];
            *(float4*)&dst[0] = make_float4(av0.x, ab0.x, av0.y, ab0.y);
            *(float4*)&dst[4] = make_float4(av0.z, ab0.z, av0.w, ab0.w);
        }
        {
            float* dst = &vb2[(2 * rg + 1) * 92 + colo * 2];
            *(float4*)&dst[0] = make_float4(av1.x, ab1.x, av1.y, ab1.y);
            *(float4*)&dst[4] = make_float4(av1.z, ab1.z, av1.w, ab1.w);
        }
    }
    __syncthreads();
    {
        const int erow = t >> 3, ecg = t & 7;
        const int oy = y0 + erow;
        const float* src = &vb2[erow * 92 + ecg * 8];
        float a00 = 0.f, a01 = 0.f, a02 = 0.f, a03 = 0.f;
        float a10 = 0.f, a11 = 0.f, a12 = 0.f, a13 = 0.f;
#pragma unroll
        for (int m = 0; m < 14; ++m) {
            float v0 = src[m * 2 + 0];
            float v1 = src[m * 2 + 1];
#pragma unroll
            for (int j = 0; j < 4; ++j) {
                const int kk = m - j;
                if (kk >= 0 && kk <= 10) {
                    if (j == 0) { a00 = fmaf(gw[kk], v0, a00); a10 = fmaf(gw[kk], v1, a10); }
                    if (j == 1) { a01 = fmaf(gw[kk], v0, a01); a11 = fmaf(gw[kk], v1, a11); }
                    if (j == 2) { a02 = fmaf(gw[kk], v0, a02); a12 = fmaf(gw[kk], v1, a12); }
                    if (j == 3) { a03 = fmaf(gw[kk], v0, a03); a13 = fmaf(gw[kk], v1, a13); }
                }
            }
        }
        if (oy < HPc) {
            size_t ob = (size_t)bi * HPWPc + (size_t)oy * HPc;
            int oxb = x0 + ecg * 4;
            if (oxb + 0 < HPc) { muf[ob + oxb + 0] = a00; ef2g[ob + oxb + 0] = a10; }
            if (oxb + 1 < HPc) { muf[ob + oxb + 1] = a01; ef2g[ob + oxb + 1] = a11; }
            if (oxb + 2 < HPc) { muf[ob + oxb + 2] = a02; ef2g[ob + oxb + 2] = a12; }
            if (oxb + 3 < HPc) { muf[ob + oxb + 3] = a03; ef2g[ob + oxb + 3] = a13; }
        }
    }
}

// ---- K5 macro machinery (no local arrays; minimal persistent registers) ----
#define T(F,J,KK,V) h##F##_##J = fmaf(G##KK, (V), h##F##_##J);
#define TM0(F,V)  T(F,0,0,V)
#define TM1(F,V)  T(F,0,1,V) T(F,1,0,V)
#define TM2(F,V)  T(F,0,2,V) T(F,1,1,V) T(F,2,0,V)
#define TM3(F,V)  T(F,0,3,V) T(F,1,2,V) T(F,2,1,V) T(F,3,0,V)
#define TM4(F,V)  T(F,0,4,V) T(F,1,3,V) T(F,2,2,V) T(F,3,1,V)
#define TM5(F,V)  T(F,0,5,V) T(F,1,4,V) T(F,2,3,V) T(F,3,2,V)
#define TM6(F,V)  T(F,0,6,V) T(F,1,5,V) T(F,2,4,V) T(F,3,3,V)
#define TM7(F,V)  T(F,0,7,V) T(F,1,6,V) T(F,2,5,V) T(F,3,4,V)
#define TM8(F,V)  T(F,0,8,V) T(F,1,7,V) T(F,2,6,V) T(F,3,5,V)
#define TM9(F,V)  T(F,0,9,V) T(F,1,8,V) T(F,2,7,V) T(F,3,6,V)
#define TM10(F,V) T(F,0,10,V) T(F,1,9,V) T(F,2,8,V) T(F,3,7,V)
#define TM11(F,V) T(F,1,10,V) T(F,2,9,V) T(F,3,8,V)
#define TM12(F,V) T(F,2,10,V) T(F,3,9,V)
#define TM13(F,V) T(F,3,10,V)

#define DECLH(J) float h0_##J = 0.f, h1_##J = 0.f, h2_##J = 0.f, h3_##J = 0.f, h4_##J = 0.f;
// persistent per-thread constants: M = mu1, S = (s1 + C2) or +inf (invalid marker)
#define DECLJ(J) float M0_##J, M1_##J, M2_##J, S0_##J, S1_##J, S2_##J;
#define SETI(I,J) { float mu1 = 0.f, e2 = 0.f; \
    if (vld) { size_t o = (size_t)(b * 3 + I) * HPWPc + (size_t)oy * HPc + ox; mu1 = muf[o]; e2 = ef2g[o]; } \
    M##I##_##J = mu1; S##I##_##J = vld ? ((e2 - mu1 * mu1) + C2v) : __builtin_inff(); }
#define SETJ(J) { int ox = ox0 + J; bool vld = (oy < HPc) && (ox < HPc); \
    SETI(0,J) SETI(1,J) SETI(2,J) }

#define SSIMI(I,J,HV) { float am = M##I##_##J * m2; \
    float num = fmaf(2.f, am, C1v) * fmaf(2.f, (HV) - am, C2v); \
    float den = fmaf(M##I##_##J, M##I##_##J, c1m2) * (S##I##_##J + s2); \
    sa##I += num * __builtin_amdgcn_rcpf(den); }
#define SSIMJ(J) { float m2 = h0_##J; float m2sq = m2 * m2; \
    float c1m2 = C1v + m2sq; float s2 = h1_##J - m2sq; \
    SSIMI(0,J,h2_##J) SSIMI(1,J,h3_##J) SSIMI(2,J,h4_##J) }

#define VSTEP(K, DOA, DOB, GA, GB) { \
    int gr = y0 + 2 * vrg + (K); gr = (gr > 255) ? 255 : gr; \
    float4 xv = *(const float4*)(xp + gr * 256 + gcb); \
    const int ro = (2 * vrg + (K)) * 44 + vcolo; \
    float4 f0 = *(const float4*)&f0in[ro]; \
    float4 f1v = *(const float4*)&f1in[ro]; \
    float4 f2v = *(const float4*)&f2in[ro]; \
    if (DOA) { float4 tv = f4scale((GA), xv); f4add(xA0, tv); f4fma(xQ0, tv, xv); \
               f4fma(p00, tv, f0); f4fma(p10, tv, f1v); f4fma(p20, tv, f2v); } \
    if (DOB) { float4 tv = f4scale((GB), xv); f4add(xA1, tv); f4fma(xQ1, tv, xv); \
               f4fma(p01, tv, f0); f4fma(p11, tv, f1v); f4fma(p21, tv, f2v); } }

// VERT/HORIZ as textual macros over STATIC __shared__ array names (no lambdas, no
// runtime pointer select) — R2 post-mortem: a `(c&1)?a:b` select through lambda captures
// degraded DS ops (conflicts 5.6e7 -> 1.38e8, VALUBusy 40 -> 28). Textual names keep
// addrspace(3) + b128 forms.
#define VERT(CC, BUF) do { if (vact) { \
    const float* xp = xb + (size_t)(CC) * HWc; \
    float4 xA0 = f4z(), xQ0 = f4z(), p00 = f4z(), p10 = f4z(), p20 = f4z(); \
    float4 xA1 = f4z(), xQ1 = f4z(), p01 = f4z(), p11 = f4z(), p21 = f4z(); \
    VSTEP(0, 1, 0, G0, G0)  VSTEP(1, 1, 1, G1, G0)  VSTEP(2, 1, 1, G2, G1) \
    VSTEP(3, 1, 1, G3, G2)  VSTEP(4, 1, 1, G4, G3)  VSTEP(5, 1, 1, G5, G4) \
    VSTEP(6, 1, 1, G6, G5)  VSTEP(7, 1, 1, G7, G6)  VSTEP(8, 1, 1, G8, G7) \
    VSTEP(9, 1, 1, G9, G8)  VSTEP(10, 1, 1, G10, G9) VSTEP(11, 0, 1, G0, G10) \
    { float* dst = &BUF[(2 * vrg + 0) * VPITCH + vcolo * 5]; \
      *(float4*)&dst[0]  = make_float4(xA0.x, xQ0.x, p00.x, p10.x); \
      *(float4*)&dst[4]  = make_float4(p20.x, xA0.y, xQ0.y, p00.y); \
      *(float4*)&dst[8]  = make_float4(p10.y, p20.y, xA0.z, xQ0.z); \
      *(float4*)&dst[12] = make_float4(p00.z, p10.z, p20.z, xA0.w); \
      *(float4*)&dst[16] = make_float4(xQ0.w, p00.w, p10.w, p20.w); } \
    { float* dst = &BUF[(2 * vrg + 1) * VPITCH + vcolo * 5]; \
      *(float4*)&dst[0]  = make_float4(xA1.x, xQ1.x, p01.x, p11.x); \
      *(float4*)&dst[4]  = make_float4(p21.x, xA1.y, xQ1.y, p01.y); \
      *(float4*)&dst[8]  = make_float4(p11.y, p21.y, xA1.z, xQ1.z); \
      *(float4*)&dst[12] = make_float4(p01.z, p11.z, p21.z, xA1.w); \
      *(float4*)&dst[16] = make_float4(xQ1.w, p01.w, p11.w, p21.w); } \
} } while (0)

#define HORIZ(CC, BUF) do { \
    const float* src = &BUF[erow * VPITCH + ecg * 20]; \
    DECLH(0) DECLH(1) DECLH(2) DECLH(3) \
    float4 L0 = *(const float4*)(src + 0); \
    TM0(0, L0.x) TM0(1, L0.y) TM0(2, L0.z) TM0(3, L0.w) \
    float4 L1 = *(const float4*)(src + 4); \
    TM0(4, L1.x) TM1(0, L1.y) TM1(1, L1.z) TM1(2, L1.w) \
    float4 L2 = *(const float4*)(src + 8); \
    TM1(3, L2.x) TM1(4, L2.y) TM2(0, L2.z) TM2(1, L2.w) \
    float4 L3 = *(const float4*)(src + 12); \
    TM2(2, L3.x) TM2(3, L3.y) TM2(4, L3.z) TM3(0, L3.w) \
    float4 L4 = *(const float4*)(src + 16); \
    TM3(1, L4.x) TM3(2, L4.y) TM3(3, L4.z) TM3(4, L4.w) \
    float4 L5 = *(const float4*)(src + 20); \
    TM4(0, L5.x) TM4(1, L5.y) TM4(2, L5.z) TM4(3, L5.w) \
    float4 L6 = *(const float4*)(src + 24); \
    TM4(4, L6.x) TM5(0, L6.y) TM5(1, L6.z) TM5(2, L6.w) \
    float4 L7 = *(const float4*)(src + 28); \
    TM5(3, L7.x) TM5(4, L7.y) TM6(0, L7.z) TM6(1, L7.w) \
    float4 L8 = *(const float4*)(src + 32); \
    TM6(2, L8.x) TM6(3, L8.y) TM6(4, L8.z) TM7(0, L8.w) \
    float4 L9 = *(const float4*)(src + 36); \
    TM7(1, L9.x) TM7(2, L9.y) TM7(3, L9.z) TM7(4, L9.w) \
    float4 L10 = *(const float4*)(src + 40); \
    TM8(0, L10.x) TM8(1, L10.y) TM8(2, L10.z) TM8(3, L10.w) \
    float4 L11 = *(const float4*)(src + 44); \
    TM8(4, L11.x) TM9(0, L11.y) TM9(1, L11.z) TM9(2, L11.w) \
    float4 L12 = *(const float4*)(src + 48); \
    TM9(3, L12.x) TM9(4, L12.y) TM10(0, L12.z) TM10(1, L12.w) \
    float4 L13 = *(const float4*)(src + 52); \
    TM10(2, L13.x) TM10(3, L13.y) TM10(4, L13.z) TM11(0, L13.w) \
    float4 L14 = *(const float4*)(src + 56); \
    TM11(1, L14.x) TM11(2, L14.y) TM11(3, L14.z) TM11(4, L14.w) \
    float4 L15 = *(const float4*)(src + 60); \
    TM12(0, L15.x) TM12(1, L15.y) TM12(2, L15.z) TM12(3, L15.w) \
    float4 L16 = *(const float4*)(src + 64); \
    TM12(4, L16.x) TM13(0, L16.y) TM13(1, L16.z) TM13(2, L16.w) \
    float4 L17 = *(const float4*)(src + 68); \
    TM13(3, L17.x) TM13(4, L17.y) \
    float sa0 = 0.f, sa1 = 0.f, sa2 = 0.f; \
    SSIMJ(0) SSIMJ(1) SSIMJ(2) SSIMJ(3) \
    sa0 = wave_sum64(sa0); \
    sa1 = wave_sum64(sa1); \
    sa2 = wave_sum64(sa2); \
    if ((t & 63) == 63) { \
        atomicAdd(&ssum[(b * 3 + 0) * 64 + (CC)], sa0); \
        atomicAdd(&ssum[(b * 3 + 1) * 64 + (CC)], sa1); \
        atomicAdd(&ssum[(b * 3 + 2) * 64 + (CC)], sa2); \
    } \
} while (0)

// K5: per (b, 32x32 tile): xf tiles staged in LDS once; full 64-channel loop.
// __launch_bounds__(256,2): 128-VGPR budget — (256,3) spills (~6.7 GB scratch traffic).
// Double-buffered vb5 via 2-unrolled channel loop with STATIC buffer names:
// one barrier per channel (65 vs 129); vert(c+1)'s global loads + FMAs share the
// scheduling region with horiz(c)'s LDS-fed FMAs -> mutual latency hiding, and the
// 80 vert-idle threads get horiz work in-region.
// LDS = 22176 + 2*32*224*4 = 79520 B -> 2 blocks/CU (159 KB < 160 KB).
// NOTE: SQ_LDS_BANK_CONFLICT ~5.1e7 is the inherent 8-phase cost of wave64 b128 LDS
// ops (1024B @ 128B/clk), NOT fixable conflicts (R0/R1 evidence).
__global__ __launch_bounds__(256, 2) void k5_main(const float* __restrict__ x, const float* __restrict__ xc,
                                                  const int* __restrict__ mask, const float* __restrict__ stats,
                                                  const float* __restrict__ muf, const float* __restrict__ ef2g,
                                                  float* __restrict__ ssum) {
    __shared__ __align__(16) float f0in[42 * 44];
    __shared__ __align__(16) float f1in[42 * 44];
    __shared__ __align__(16) float f2in[42 * 44];
    __shared__ __align__(16) float vb5a[32 * VPITCH];
    __shared__ __align__(16) float vb5b[32 * VPITCH];
    const int t = threadIdx.x;
    const int b = blockIdx.z;
    const int y0 = blockIdx.y * 32, x0 = blockIdx.x * 32;
    // gauss weights as named scalars (same numerics as gauss11)
    const double e0 = exp(-25.0 / 4.5), e1 = exp(-16.0 / 4.5), e2d = exp(-9.0 / 4.5),
                 e3 = exp(-4.0 / 4.5), e4 = exp(-1.0 / 4.5);
    const double sg = 1.0 + 2.0 * (e0 + e1 + e2d + e3 + e4);
    const float G0 = (float)(e0 / sg), G1 = (float)(e1 / sg), G2 = (float)(e2d / sg),
                G3 = (float)(e3 / sg), G4 = (float)(e4 / sg), G5 = (float)(1.0 / sg);
    const float G6 = G4, G7 = G3, G8 = G2, G9 = G1, G10 = G0;
    // per-(b,i) normalization constants
    const float nst = stats[b * 8 + 0];
    const float s1a = stats[b * 8 + 1], s2a = stats[b * 8 + 4];
    const float s1b = stats[b * 8 + 2], s2b = stats[b * 8 + 5];
    const float s1c = stats[b * 8 + 3], s2c = stats[b * 8 + 6];
    const float mean0 = s1a / nst, rstd0 = rsqrtf((s2a - s1a * s1a / nst) / (nst - 1.0f));
    const float mean1 = s1b / nst, rstd1 = rsqrtf((s2b - s1b * s1b / nst) / (nst - 1.0f));
    const float mean2 = s1c / nst, rstd2 = rsqrtf((s2c - s1c * s1c / nst) / (nst - 1.0f));
    // stage normalized xf tiles (once per block)
    for (int q = t; q < 42 * 11; q += 256) {
        int row = q / 11, cg = q % 11;
        int gr = min(y0 + row, 255), gc = min(x0 + cg * 4, 252);
        int go = gr * 256 + gc;
        int lo = row * 44 + cg * 4;
        int4 mv = *(const int4*)(mask + (size_t)b * HWc + go);
        float m0 = (float)mv.x, m1 = (float)mv.y, m2 = (float)mv.z, m3 = (float)mv.w;
        float4 v0 = *(const float4*)(xc + (size_t)(b * 3 + 0) * HWc + go);
        v0.x = (v0.x - mean0) * rstd0 * m0; v0.y = (v0.y - mean0) * rstd0 * m1;
        v0.z = (v0.z - mean0) * rstd0 * m2; v0.w = (v0.w - mean0) * rstd0 * m3;
        *(float4*)&f0in[lo] = v0;
        float4 v1 = *(const float4*)(xc + (size_t)(b * 3 + 1) * HWc + go);
        v1.x = (v1.x - mean1) * rstd1 * m0; v1.y = (v1.y - mean1) * rstd1 * m1;
        v1.z = (v1.z - mean1) * rstd1 * m2; v1.w = (v1.w - mean1) * rstd1 * m3;
        *(float4*)&f1in[lo] = v1;
        float4 v2 = *(const float4*)(xc + (size_t)(b * 3 + 2) * HWc + go);
        v2.x = (v2.x - mean2) * rstd2 * m0; v2.y = (v2.y - mean2) * rstd2 * m1;
        v2.z = (v2.z - mean2) * rstd2 * m2; v2.w = (v2.w - mean2) * rstd2 * m3;
        *(float4*)&f2in[lo] = v2;
    }
    // per-thread c-independent eval constants (named scalars, 24 persistent regs)
    const int erow = t >> 3, ecg = t & 7;
    const int oy = y0 + erow;
    const int ox0 = x0 + ecg * 4;
    DECLJ(0) DECLJ(1) DECLJ(2) DECLJ(3)
    SETJ(0) SETJ(1) SETJ(2) SETJ(3)
    const float* xb = x + (size_t)b * Cn * HWc;
    const int vrg = t / 11, vcg = t % 11, vcolo = vcg * 4;
    const int gcb = min(x0 + vcolo, 252);
    const bool vact = (t < 176);

    __syncthreads();           // f-tiles staged
    VERT(0, vb5a);             // prologue: fill buffer A
#pragma unroll 1
    for (int c = 0; c < Cn; c += 2) {
        __syncthreads();       // vb5a written (by prologue or tail of prev iter)
        VERT(c + 1, vb5b);     // next channel into B while A is consumed
        HORIZ(c, vb5a);
        __syncthreads();       // vb5b written; vb5a consumed
        if (c + 2 < Cn) VERT(c + 2, vb5a);
        HORIZ(c + 1, vb5b);
    }
}

// K6: normalize ssim sums -> ssim_info output; conv3 over C + MLP head -> h output
__global__ __launch_bounds__(512) void k6_head(const float* __restrict__ ssum, const float* __restrict__ cw,
                                               const float* __restrict__ w1, const float* __restrict__ b1,
                                               const float* __restrict__ w2, const float* __restrict__ b2,
                                               float* __restrict__ out) {
    __shared__ float si[1536];
    __shared__ float h0[512];
    __shared__ float h1[512];
    const int t = threadIdx.x;
    const float inv = 1.0f / (float)HPWPc;
    for (int idx = t; idx < 1536; idx += 512) {
        float v = ssum[idx] * inv;
        si[idx] = v;
        out[512 + idx] = v;
    }
    __syncthreads();
    const int b = t >> 6, y = t & 63;
    float acc = 0.f;
#pragma unroll
    for (int i = 0; i < 3; ++i) {
#pragma unroll
        for (int kh = 0; kh < 3; ++kh) {
            int yy = y + kh - 1;
            if (yy >= 0 && yy < 64) acc = fmaf(si[(b * 3 + i) * 64 + yy], cw[i * 3 + kh], acc);
        }
    }
    h0[t] = fmaxf(acc, 0.f);
    __syncthreads();
    float a1 = b1[y];
    for (int c = 0; c < 64; ++c) a1 = fmaf(h0[(b << 6) + c], w1[(y << 6) + c], a1);
    h1[t] = fmaxf(a1, 0.f);
    __syncthreads();
    float a2 = b2[y];
    for (int c = 0; c < 64; ++c) a2 = fmaf(h1[(b << 6) + c], w2[(y << 6) + c], a2);
    out[t] = 1.f / (1.f + expf(-a2));
}

extern "C" void kernel_launch(void* const* d_in, const int* in_sizes, int n_in,
                              void* d_out, int out_size, void* d_ws, size_t ws_size,
                              hipStream_t stream) {
    const float* x      = (const float*)d_in[0];
    const int*   mask   = (const int*)d_in[1];
    const float* conv_w = (const float*)d_in[2];
    const float* w1     = (const float*)d_in[3];
    const float* b1     = (const float*)d_in[4];
    const float* w2     = (const float*)d_in[5];
    const float* b2     = (const float*)d_in[6];
    float* out = (float*)d_out;

    float* wsf   = (float*)d_ws;
    float* stats = wsf;                       // 64 floats (8 b x 8 slots)
    float* ssum  = wsf + 64;                  // 1536 floats
    float* xcf   = wsf + 1600;                // 8*3*65536 raw xc (max/mean/min)
    float* muf   = xcf + (size_t)Bn * 3 * HWc;      // 8*3*60516
    float* ef2   = muf + (size_t)Bn * 3 * HPWPc;    // 8*3*60516

    hipMemsetAsync(d_ws, 0, 6400, stream);  // stats + ssum accumulators

    k1_stats<<<dim3(64, 8), 256, 0, stream>>>(x, mask, xcf, stats);
    k4_blur3<<<dim3(8, 8, 24), 256, 0, stream>>>(xcf, mask, stats, muf, ef2);
    k5_main<<<dim3(8, 8, 8), 256, 0, stream>>>(x, xcf, mask, stats, muf, ef2, ssum);
    k6_head<<<1, 512, 0, stream>>>(ssum, conv_w, w1, b1, w2, b2, out);
}

// Round 4
// 643.716 us; speedup vs baseline: 1.4575x; 1.0203x over previous
//
#include <hip/hip_runtime.h>
#include <cmath>

#define Bn   8
#define Cn   64
#define HWc  65536      // 256*256
#define HPc  246        // 256-11+1
#define HPWPc 60516     // 246*246
#define C1v  0.01f      // (0.01*10)^2
#define C2v  0.09f      // (0.03*10)^2
#define VPITCH 224      // vb5 row pitch (floats); writes reach 219+, reads 211+ -> 224 fits.
                        // LDS = 22176 (f-tiles) + 32*224*4 = 50848 B.

// 11-tap normalized gaussian, sigma=1.5 (double, then f32 cast — matches numpy)
static __device__ __forceinline__ void gauss11(float* gw) {
    double gg[11]; double s = 0.0;
#pragma unroll
    for (int j = 0; j < 11; ++j) { double d = (double)(j - 5); gg[j] = exp(-(d * d) / 4.5); s += gg[j]; }
#pragma unroll
    for (int j = 0; j < 11; ++j) gw[j] = (float)(gg[j] / s);
}

static __device__ __forceinline__ float4 f4z() { return make_float4(0.f, 0.f, 0.f, 0.f); }
static __device__ __forceinline__ float4 f4scale(float g, const float4 v) {
    return make_float4(g * v.x, g * v.y, g * v.z, g * v.w);
}
static __device__ __forceinline__ void f4add(float4& a, const float4 v) {
    a.x += v.x; a.y += v.y; a.z += v.z; a.w += v.w;
}
static __device__ __forceinline__ void f4fma(float4& a, const float4 u, const float4 v) {
    a.x = fmaf(u.x, v.x, a.x); a.y = fmaf(u.y, v.y, a.y);
    a.z = fmaf(u.z, v.z, a.z); a.w = fmaf(u.w, v.w, a.w);
}

// wave64 sum via DPP (VALU pipe, no LDS traffic). Result valid in lane 63.
static __device__ __forceinline__ float wave_sum64(float v) {
    v += __int_as_float(__builtin_amdgcn_update_dpp(0, __float_as_int(v), 0x111, 0xf, 0xf, true)); // row_shr:1
    v += __int_as_float(__builtin_amdgcn_update_dpp(0, __float_as_int(v), 0x112, 0xf, 0xf, true)); // row_shr:2
    v += __int_as_float(__builtin_amdgcn_update_dpp(0, __float_as_int(v), 0x114, 0xf, 0xf, true)); // row_shr:4
    v += __int_as_float(__builtin_amdgcn_update_dpp(0, __float_as_int(v), 0x118, 0xf, 0xf, true)); // row_shr:8
    v += __int_as_float(__builtin_amdgcn_update_dpp(0, __float_as_int(v), 0x142, 0xf, 0xf, true)); // row_bcast:15
    v += __int_as_float(__builtin_amdgcn_update_dpp(0, __float_as_int(v), 0x143, 0xf, 0xf, true)); // row_bcast:31
    return v;
}

// K1: channel max/mean/min (-> xcf planes, RAW) + masked stats atomics
__global__ __launch_bounds__(256) void k1_stats(const float* __restrict__ x, const int* __restrict__ mask,
                                                float* __restrict__ xcf, float* __restrict__ stats) {
    const int b = blockIdx.y;
    const int p0 = blockIdx.x * 1024 + threadIdx.x * 4;
    const float4* xp = (const float4*)(x + (size_t)b * Cn * HWc) + (p0 >> 2);
    float4 v = xp[0];
    float4 vmax = v, vmin = v, vsum = v;
#pragma unroll 4
    for (int c = 1; c < Cn; ++c) {
        float4 u = xp[(size_t)c * (HWc / 4)];
        vmax.x = fmaxf(vmax.x, u.x); vmax.y = fmaxf(vmax.y, u.y);
        vmax.z = fmaxf(vmax.z, u.z); vmax.w = fmaxf(vmax.w, u.w);
        vmin.x = fminf(vmin.x, u.x); vmin.y = fminf(vmin.y, u.y);
        vmin.z = fminf(vmin.z, u.z); vmin.w = fminf(vmin.w, u.w);
        vsum.x += u.x; vsum.y += u.y; vsum.z += u.z; vsum.w += u.w;
    }
    float4 vmean = make_float4(vsum.x * (1.f / 64.f), vsum.y * (1.f / 64.f),
                               vsum.z * (1.f / 64.f), vsum.w * (1.f / 64.f));
    *(float4*)(xcf + (size_t)(b * 3 + 0) * HWc + p0) = vmax;
    *(float4*)(xcf + (size_t)(b * 3 + 1) * HWc + p0) = vmean;
    *(float4*)(xcf + (size_t)(b * 3 + 2) * HWc + p0) = vmin;
    int4 mv = *(const int4*)(mask + (size_t)b * HWc + p0);
    float m0 = (float)mv.x, m1 = (float)mv.y, m2 = (float)mv.z, m3 = (float)mv.w;
    float r[7];
    r[0] = m0 + m1 + m2 + m3;
    r[1] = vmax.x * m0 + vmax.y * m1 + vmax.z * m2 + vmax.w * m3;
    r[2] = vmean.x * m0 + vmean.y * m1 + vmean.z * m2 + vmean.w * m3;
    r[3] = vmin.x * m0 + vmin.y * m1 + vmin.z * m2 + vmin.w * m3;
    r[4] = vmax.x * vmax.x * m0 + vmax.y * vmax.y * m1 + vmax.z * vmax.z * m2 + vmax.w * vmax.w * m3;
    r[5] = vmean.x * vmean.x * m0 + vmean.y * vmean.y * m1 + vmean.z * vmean.z * m2 + vmean.w * vmean.w * m3;
    r[6] = vmin.x * vmin.x * m0 + vmin.y * vmin.y * m1 + vmin.z * vmin.z * m2 + vmin.w * vmin.w * m3;
#pragma unroll
    for (int k = 0; k < 7; ++k) {
        float vv = wave_sum64(r[k]);
        if ((threadIdx.x & 63) == 63) atomicAdd(&stats[b * 8 + k], vv);
    }
}

// K4: mu_f = blur(xf), ef2 = blur(xf^2); xf computed inline from raw xc + mask + stats.
__global__ __launch_bounds__(256) void k4_blur3(const float* __restrict__ xc, const int* __restrict__ mask,
                                                const float* __restrict__ stats,
                                                float* __restrict__ muf, float* __restrict__ ef2g) {
    __shared__ __align__(16) float vb2[32 * 92];
    const int t = threadIdx.x;
    const int bi = blockIdx.z, b = bi / 3, i = bi % 3;
    const int y0 = blockIdx.y * 32, x0 = blockIdx.x * 32;
    float gw[11]; gauss11(gw);
    const float nst = stats[b * 8 + 0];
    const float s1 = stats[b * 8 + 1 + i], s2 = stats[b * 8 + 4 + i];
    const float mean = s1 / nst;
    const float rstd = rsqrtf((s2 - s1 * s1 / nst) / (nst - 1.0f));
    if (t < 176) {
        const int rg = t / 11, cg = t % 11, colo = cg * 4;
        const int gcb = min(x0 + colo, 252);
        const float* xp = xc + (size_t)bi * HWc;
        const int* mp = mask + (size_t)b * HWc;
        float4 av0 = f4z(), ab0 = f4z(), av1 = f4z(), ab1 = f4z();
#pragma unroll
        for (int k = 0; k < 12; ++k) {
            int gr = min(y0 + 2 * rg + k, 255);
            float4 v = *(const float4*)(xp + gr * 256 + gcb);
            int4 mv = *(const int4*)(mp + gr * 256 + gcb);
            float4 f;
            f.x = (v.x - mean) * rstd * (float)mv.x;
            f.y = (v.y - mean) * rstd * (float)mv.y;
            f.z = (v.z - mean) * rstd * (float)mv.z;
            f.w = (v.w - mean) * rstd * (float)mv.w;
            if (k <= 10) { float4 tv = f4scale(gw[k], f); f4add(av0, tv); f4fma(ab0, tv, f); }
            if (k >= 1)  { float4 tv = f4scale(gw[k - 1], f); f4add(av1, tv); f4fma(ab1, tv, f); }
        }
        {
            float* dst = &vb2[(2 * rg + 0) * 92 + colo * 2];
            *(float4*)&dst[0] = make_float4(av0.x, ab0.x, av0.y, ab0.y);
            *(float4*)&dst[4] = make_float4(av0.z, ab0.z, av0.w, ab0.w);
        }
        {
            float* dst = &vb2[(2 * rg + 1) * 92 + colo * 2];
            *(float4*)&dst[0] = make_float4(av1.x, ab1.x, av1.y, ab1.y);
            *(float4*)&dst[4] = make_float4(av1.z, ab1.z, av1.w, ab1.w);
        }
    }
    __syncthreads();
    {
        const int erow = t >> 3, ecg = t & 7;
        const int oy = y0 + erow;
        const float* src = &vb2[erow * 92 + ecg * 8];
        float a00 = 0.f, a01 = 0.f, a02 = 0.f, a03 = 0.f;
        float a10 = 0.f, a11 = 0.f, a12 = 0.f, a13 = 0.f;
#pragma unroll
        for (int m = 0; m < 14; ++m) {
            float v0 = src[m * 2 + 0];
            float v1 = src[m * 2 + 1];
#pragma unroll
            for (int j = 0; j < 4; ++j) {
                const int kk = m - j;
                if (kk >= 0 && kk <= 10) {
                    if (j == 0) { a00 = fmaf(gw[kk], v0, a00); a10 = fmaf(gw[kk], v1, a10); }
                    if (j == 1) { a01 = fmaf(gw[kk], v0, a01); a11 = fmaf(gw[kk], v1, a11); }
                    if (j == 2) { a02 = fmaf(gw[kk], v0, a02); a12 = fmaf(gw[kk], v1, a12); }
                    if (j == 3) { a03 = fmaf(gw[kk], v0, a03); a13 = fmaf(gw[kk], v1, a13); }
                }
            }
        }
        if (oy < HPc) {
            size_t ob = (size_t)bi * HPWPc + (size_t)oy * HPc;
            int oxb = x0 + ecg * 4;
            if (oxb + 0 < HPc) { muf[ob + oxb + 0] = a00; ef2g[ob + oxb + 0] = a10; }
            if (oxb + 1 < HPc) { muf[ob + oxb + 1] = a01; ef2g[ob + oxb + 1] = a11; }
            if (oxb + 2 < HPc) { muf[ob + oxb + 2] = a02; ef2g[ob + oxb + 2] = a12; }
            if (oxb + 3 < HPc) { muf[ob + oxb + 3] = a03; ef2g[ob + oxb + 3] = a13; }
        }
    }
}

// ---- K5 macro machinery (no local arrays; minimal persistent registers) ----
#define T(F,J,KK,V) h##F##_##J = fmaf(G##KK, (V), h##F##_##J);
#define TM0(F,V)  T(F,0,0,V)
#define TM1(F,V)  T(F,0,1,V) T(F,1,0,V)
#define TM2(F,V)  T(F,0,2,V) T(F,1,1,V) T(F,2,0,V)
#define TM3(F,V)  T(F,0,3,V) T(F,1,2,V) T(F,2,1,V) T(F,3,0,V)
#define TM4(F,V)  T(F,0,4,V) T(F,1,3,V) T(F,2,2,V) T(F,3,1,V)
#define TM5(F,V)  T(F,0,5,V) T(F,1,4,V) T(F,2,3,V) T(F,3,2,V)
#define TM6(F,V)  T(F,0,6,V) T(F,1,5,V) T(F,2,4,V) T(F,3,3,V)
#define TM7(F,V)  T(F,0,7,V) T(F,1,6,V) T(F,2,5,V) T(F,3,4,V)
#define TM8(F,V)  T(F,0,8,V) T(F,1,7,V) T(F,2,6,V) T(F,3,5,V)
#define TM9(F,V)  T(F,0,9,V) T(F,1,8,V) T(F,2,7,V) T(F,3,6,V)
#define TM10(F,V) T(F,0,10,V) T(F,1,9,V) T(F,2,8,V) T(F,3,7,V)
#define TM11(F,V) T(F,1,10,V) T(F,2,9,V) T(F,3,8,V)
#define TM12(F,V) T(F,2,10,V) T(F,3,9,V)
#define TM13(F,V) T(F,3,10,V)

#define DECLH(J) float h0_##J = 0.f, h1_##J = 0.f, h2_##J = 0.f, h3_##J = 0.f, h4_##J = 0.f;
// persistent per-thread constants: M = mu1, S = (s1 + C2) or +inf (invalid marker)
#define DECLJ(J) float M0_##J, M1_##J, M2_##J, S0_##J, S1_##J, S2_##J;
#define SETI(I,J) { float mu1 = 0.f, e2 = 0.f; \
    if (vld) { size_t o = (size_t)(b * 3 + I) * HPWPc + (size_t)oy * HPc + ox; mu1 = muf[o]; e2 = ef2g[o]; } \
    M##I##_##J = mu1; S##I##_##J = vld ? ((e2 - mu1 * mu1) + C2v) : __builtin_inff(); }
#define SETJ(J) { int ox = ox0 + J; bool vld = (oy < HPc) && (ox < HPc); \
    SETI(0,J) SETI(1,J) SETI(2,J) }

#define SSIMI(I,J,HV) { float am = M##I##_##J * m2; \
    float num = fmaf(2.f, am, C1v) * fmaf(2.f, (HV) - am, C2v); \
    float den = fmaf(M##I##_##J, M##I##_##J, c1m2) * (S##I##_##J + s2); \
    sa##I += num * __builtin_amdgcn_rcpf(den); }
#define SSIMJ(J) { float m2 = h0_##J; float m2sq = m2 * m2; \
    float c1m2 = C1v + m2sq; float s2 = h1_##J - m2sq; \
    SSIMI(0,J,h2_##J) SSIMI(1,J,h3_##J) SSIMI(2,J,h4_##J) }

// T14 async-STAGE split: XLOAD issues next channel's 12 global b128 loads into NAMED
// registers xv0..xv11 (no arrays -> no scratch); VCOMP consumes them + f-tile LDS reads.
// XLOAD(c+1) is placed before HORIZ(c): ~900-cycle HBM latency hides under HORIZ's
// ~1200+ VALU cycles + a barrier. (R3 post-mortem: vert global-load stall ≈ 1800 cyc/wave
// per channel explains the measured 45% VALUBusy ceiling.)
#define XROW(K) { int gr = y0 + 2 * vrg + (K); gr = (gr > 255) ? 255 : gr; \
    xv##K = *(const float4*)(xp + gr * 256 + gcb); }
#define XLOAD(CC) do { if (vact) { \
    int cc = (CC); if (cc > Cn - 1) cc = Cn - 1; \
    const float* xp = xb + (size_t)cc * HWc; \
    XROW(0) XROW(1) XROW(2) XROW(3) XROW(4) XROW(5) \
    XROW(6) XROW(7) XROW(8) XROW(9) XROW(10) XROW(11) \
} } while (0)

#define VSTEP(K, DOA, DOB, GA, GB) { \
    float4 xv = xv##K; \
    const int ro = (2 * vrg + (K)) * 44 + vcolo; \
    float4 f0 = *(const float4*)&f0in[ro]; \
    float4 f1v = *(const float4*)&f1in[ro]; \
    float4 f2v = *(const float4*)&f2in[ro]; \
    if (DOA) { float4 tv = f4scale((GA), xv); f4add(xA0, tv); f4fma(xQ0, tv, xv); \
               f4fma(p00, tv, f0); f4fma(p10, tv, f1v); f4fma(p20, tv, f2v); } \
    if (DOB) { float4 tv = f4scale((GB), xv); f4add(xA1, tv); f4fma(xQ1, tv, xv); \
               f4fma(p01, tv, f0); f4fma(p11, tv, f1v); f4fma(p21, tv, f2v); } }

// VCOMP over STATIC __shared__ array name (R2 lesson: no runtime LDS pointer selects).
#define VCOMP(BUF) do { if (vact) { \
    float4 xA0 = f4z(), xQ0 = f4z(), p00 = f4z(), p10 = f4z(), p20 = f4z(); \
    float4 xA1 = f4z(), xQ1 = f4z(), p01 = f4z(), p11 = f4z(), p21 = f4z(); \
    VSTEP(0, 1, 0, G0, G0)  VSTEP(1, 1, 1, G1, G0)  VSTEP(2, 1, 1, G2, G1) \
    VSTEP(3, 1, 1, G3, G2)  VSTEP(4, 1, 1, G4, G3)  VSTEP(5, 1, 1, G5, G4) \
    VSTEP(6, 1, 1, G6, G5)  VSTEP(7, 1, 1, G7, G6)  VSTEP(8, 1, 1, G8, G7) \
    VSTEP(9, 1, 1, G9, G8)  VSTEP(10, 1, 1, G10, G9) VSTEP(11, 0, 1, G0, G10) \
    { float* dst = &BUF[(2 * vrg + 0) * VPITCH + vcolo * 5]; \
      *(float4*)&dst[0]  = make_float4(xA0.x, xQ0.x, p00.x, p10.x); \
      *(float4*)&dst[4]  = make_float4(p20.x, xA0.y, xQ0.y, p00.y); \
      *(float4*)&dst[8]  = make_float4(p10.y, p20.y, xA0.z, xQ0.z); \
      *(float4*)&dst[12] = make_float4(p00.z, p10.z, p20.z, xA0.w); \
      *(float4*)&dst[16] = make_float4(xQ0.w, p00.w, p10.w, p20.w); } \
    { float* dst = &BUF[(2 * vrg + 1) * VPITCH + vcolo * 5]; \
      *(float4*)&dst[0]  = make_float4(xA1.x, xQ1.x, p01.x, p11.x); \
      *(float4*)&dst[4]  = make_float4(p21.x, xA1.y, xQ1.y, p01.y); \
      *(float4*)&dst[8]  = make_float4(p11.y, p21.y, xA1.z, xQ1.z); \
      *(float4*)&dst[12] = make_float4(p01.z, p11.z, p21.z, xA1.w); \
      *(float4*)&dst[16] = make_float4(xQ1.w, p01.w, p11.w, p21.w); } \
} } while (0)

#define HORIZ(CC, BUF) do { \
    const float* src = &BUF[erow * VPITCH + ecg * 20]; \
    DECLH(0) DECLH(1) DECLH(2) DECLH(3) \
    float4 L0 = *(const float4*)(src + 0); \
    TM0(0, L0.x) TM0(1, L0.y) TM0(2, L0.z) TM0(3, L0.w) \
    float4 L1 = *(const float4*)(src + 4); \
    TM0(4, L1.x) TM1(0, L1.y) TM1(1, L1.z) TM1(2, L1.w) \
    float4 L2 = *(const float4*)(src + 8); \
    TM1(3, L2.x) TM1(4, L2.y) TM2(0, L2.z) TM2(1, L2.w) \
    float4 L3 = *(const float4*)(src + 12); \
    TM2(2, L3.x) TM2(3, L3.y) TM2(4, L3.z) TM3(0, L3.w) \
    float4 L4 = *(const float4*)(src + 16); \
    TM3(1, L4.x) TM3(2, L4.y) TM3(3, L4.z) TM3(4, L4.w) \
    float4 L5 = *(const float4*)(src + 20); \
    TM4(0, L5.x) TM4(1, L5.y) TM4(2, L5.z) TM4(3, L5.w) \
    float4 L6 = *(const float4*)(src + 24); \
    TM4(4, L6.x) TM5(0, L6.y) TM5(1, L6.z) TM5(2, L6.w) \
    float4 L7 = *(const float4*)(src + 28); \
    TM5(3, L7.x) TM5(4, L7.y) TM6(0, L7.z) TM6(1, L7.w) \
    float4 L8 = *(const float4*)(src + 32); \
    TM6(2, L8.x) TM6(3, L8.y) TM6(4, L8.z) TM7(0, L8.w) \
    float4 L9 = *(const float4*)(src + 36); \
    TM7(1, L9.x) TM7(2, L9.y) TM7(3, L9.z) TM7(4, L9.w) \
    float4 L10 = *(const float4*)(src + 40); \
    TM8(0, L10.x) TM8(1, L10.y) TM8(2, L10.z) TM8(3, L10.w) \
    float4 L11 = *(const float4*)(src + 44); \
    TM8(4, L11.x) TM9(0, L11.y) TM9(1, L11.z) TM9(2, L11.w) \
    float4 L12 = *(const float4*)(src + 48); \
    TM9(3, L12.x) TM9(4, L12.y) TM10(0, L12.z) TM10(1, L12.w) \
    float4 L13 = *(const float4*)(src + 52); \
    TM10(2, L13.x) TM10(3, L13.y) TM10(4, L13.z) TM11(0, L13.w) \
    float4 L14 = *(const float4*)(src + 56); \
    TM11(1, L14.x) TM11(2, L14.y) TM11(3, L14.z) TM11(4, L14.w) \
    float4 L15 = *(const float4*)(src + 60); \
    TM12(0, L15.x) TM12(1, L15.y) TM12(2, L15.z) TM12(3, L15.w) \
    float4 L16 = *(const float4*)(src + 64); \
    TM12(4, L16.x) TM13(0, L16.y) TM13(1, L16.z) TM13(2, L16.w) \
    float4 L17 = *(const float4*)(src + 68); \
    TM13(3, L17.x) TM13(4, L17.y) \
    float sa0 = 0.f, sa1 = 0.f, sa2 = 0.f; \
    SSIMJ(0) SSIMJ(1) SSIMJ(2) SSIMJ(3) \
    sa0 = wave_sum64(sa0); \
    sa1 = wave_sum64(sa1); \
    sa2 = wave_sum64(sa2); \
    if ((t & 63) == 63) { \
        atomicAdd(&ssum[(b * 3 + 0) * 64 + (CC)], sa0); \
        atomicAdd(&ssum[(b * 3 + 1) * 64 + (CC)], sa1); \
        atomicAdd(&ssum[(b * 3 + 2) * 64 + (CC)], sa2); \
    } \
} while (0)

// K5: per (b, 32x32 tile): xf tiles staged in LDS once; full 64-channel loop.
// __launch_bounds__(256,2): 128-VGPR budget — (256,3) spills (~6.7 GB scratch traffic).
// Structure per channel: VCOMP(c) [consumes prefetched xv regs]; XLOAD(c+1); bar;
// HORIZ(c); bar. The prefetched loads stay in flight across HORIZ + barrier.
// LDS = 22176 + 28672 = 50848 B.
// NOTE: SQ_LDS_BANK_CONFLICT ~5.1e7 is the inherent 8-phase cost of wave64 b128 LDS
// ops (1024B @ 128B/clk), NOT fixable conflicts (R0/R1 evidence). Barrier count is
// NOT the bottleneck (R3 evidence: 65 vs 129 barriers = same perf).
__global__ __launch_bounds__(256, 2) void k5_main(const float* __restrict__ x, const float* __restrict__ xc,
                                                  const int* __restrict__ mask, const float* __restrict__ stats,
                                                  const float* __restrict__ muf, const float* __restrict__ ef2g,
                                                  float* __restrict__ ssum) {
    __shared__ __align__(16) float f0in[42 * 44];
    __shared__ __align__(16) float f1in[42 * 44];
    __shared__ __align__(16) float f2in[42 * 44];
    __shared__ __align__(16) float vb5[32 * VPITCH];
    const int t = threadIdx.x;
    const int b = blockIdx.z;
    const int y0 = blockIdx.y * 32, x0 = blockIdx.x * 32;
    // gauss weights as named scalars (same numerics as gauss11)
    const double e0 = exp(-25.0 / 4.5), e1 = exp(-16.0 / 4.5), e2d = exp(-9.0 / 4.5),
                 e3 = exp(-4.0 / 4.5), e4 = exp(-1.0 / 4.5);
    const double sg = 1.0 + 2.0 * (e0 + e1 + e2d + e3 + e4);
    const float G0 = (float)(e0 / sg), G1 = (float)(e1 / sg), G2 = (float)(e2d / sg),
                G3 = (float)(e3 / sg), G4 = (float)(e4 / sg), G5 = (float)(1.0 / sg);
    const float G6 = G4, G7 = G3, G8 = G2, G9 = G1, G10 = G0;
    // per-(b,i) normalization constants
    const float nst = stats[b * 8 + 0];
    const float s1a = stats[b * 8 + 1], s2a = stats[b * 8 + 4];
    const float s1b = stats[b * 8 + 2], s2b = stats[b * 8 + 5];
    const float s1c = stats[b * 8 + 3], s2c = stats[b * 8 + 6];
    const float mean0 = s1a / nst, rstd0 = rsqrtf((s2a - s1a * s1a / nst) / (nst - 1.0f));
    const float mean1 = s1b / nst, rstd1 = rsqrtf((s2b - s1b * s1b / nst) / (nst - 1.0f));
    const float mean2 = s1c / nst, rstd2 = rsqrtf((s2c - s1c * s1c / nst) / (nst - 1.0f));
    // stage normalized xf tiles (once per block)
    for (int q = t; q < 42 * 11; q += 256) {
        int row = q / 11, cg = q % 11;
        int gr = min(y0 + row, 255), gc = min(x0 + cg * 4, 252);
        int go = gr * 256 + gc;
        int lo = row * 44 + cg * 4;
        int4 mv = *(const int4*)(mask + (size_t)b * HWc + go);
        float m0 = (float)mv.x, m1 = (float)mv.y, m2 = (float)mv.z, m3 = (float)mv.w;
        float4 v0 = *(const float4*)(xc + (size_t)(b * 3 + 0) * HWc + go);
        v0.x = (v0.x - mean0) * rstd0 * m0; v0.y = (v0.y - mean0) * rstd0 * m1;
        v0.z = (v0.z - mean0) * rstd0 * m2; v0.w = (v0.w - mean0) * rstd0 * m3;
        *(float4*)&f0in[lo] = v0;
        float4 v1 = *(const float4*)(xc + (size_t)(b * 3 + 1) * HWc + go);
        v1.x = (v1.x - mean1) * rstd1 * m0; v1.y = (v1.y - mean1) * rstd1 * m1;
        v1.z = (v1.z - mean1) * rstd1 * m2; v1.w = (v1.w - mean1) * rstd1 * m3;
        *(float4*)&f1in[lo] = v1;
        float4 v2 = *(const float4*)(xc + (size_t)(b * 3 + 2) * HWc + go);
        v2.x = (v2.x - mean2) * rstd2 * m0; v2.y = (v2.y - mean2) * rstd2 * m1;
        v2.z = (v2.z - mean2) * rstd2 * m2; v2.w = (v2.w - mean2) * rstd2 * m3;
        *(float4*)&f2in[lo] = v2;
    }
    // per-thread c-independent eval constants (named scalars, 24 persistent regs)
    const int erow = t >> 3, ecg = t & 7;
    const int oy = y0 + erow;
    const int ox0 = x0 + ecg * 4;
    DECLJ(0) DECLJ(1) DECLJ(2) DECLJ(3)
    SETJ(0) SETJ(1) SETJ(2) SETJ(3)
    const float* xb = x + (size_t)b * Cn * HWc;
    const int vrg = t / 11, vcg = t % 11, vcolo = vcg * 4;
    const int gcb = min(x0 + vcolo, 252);
    const bool vact = (t < 176);
    float4 xv0, xv1, xv2, xv3, xv4, xv5, xv6, xv7, xv8, xv9, xv10, xv11;

    XLOAD(0);                  // prefetch channel 0 (overlaps staging + SETJ latency)
    __syncthreads();           // f-tiles staged
#pragma unroll 1
    for (int c = 0; c < Cn; ++c) {
        VCOMP(vb5);            // consume xv(c); vert compute + LDS write
        XLOAD(c + 1);          // issue next channel's loads (clamped at c=63: redundant, L2-hot)
        __syncthreads();       // vb5 written
        HORIZ(c, vb5);         // ~1200+ VALU cycles/SIMD hide the in-flight loads
        __syncthreads();       // vb5 consumed before next VCOMP overwrites
    }
}

// K6: normalize ssim sums -> ssim_info output; conv3 over C + MLP head -> h output
__global__ __launch_bounds__(512) void k6_head(const float* __restrict__ ssum, const float* __restrict__ cw,
                                               const float* __restrict__ w1, const float* __restrict__ b1,
                                               const float* __restrict__ w2, const float* __restrict__ b2,
                                               float* __restrict__ out) {
    __shared__ float si[1536];
    __shared__ float h0[512];
    __shared__ float h1[512];
    const int t = threadIdx.x;
    const float inv = 1.0f / (float)HPWPc;
    for (int idx = t; idx < 1536; idx += 512) {
        float v = ssum[idx] * inv;
        si[idx] = v;
        out[512 + idx] = v;
    }
    __syncthreads();
    const int b = t >> 6, y = t & 63;
    float acc = 0.f;
#pragma unroll
    for (int i = 0; i < 3; ++i) {
#pragma unroll
        for (int kh = 0; kh < 3; ++kh) {
            int yy = y + kh - 1;
            if (yy >= 0 && yy < 64) acc = fmaf(si[(b * 3 + i) * 64 + yy], cw[i * 3 + kh], acc);
        }
    }
    h0[t] = fmaxf(acc, 0.f);
    __syncthreads();
    float a1 = b1[y];
    for (int c = 0; c < 64; ++c) a1 = fmaf(h0[(b << 6) + c], w1[(y << 6) + c], a1);
    h1[t] = fmaxf(a1, 0.f);
    __syncthreads();
    float a2 = b2[y];
    for (int c = 0; c < 64; ++c) a2 = fmaf(h1[(b << 6) + c], w2[(y << 6) + c], a2);
    out[t] = 1.f / (1.f + expf(-a2));
}

extern "C" void kernel_launch(void* const* d_in, const int* in_sizes, int n_in,
                              void* d_out, int out_size, void* d_ws, size_t ws_size,
                              hipStream_t stream) {
    const float* x      = (const float*)d_in[0];
    const int*   mask   = (const int*)d_in[1];
    const float* conv_w = (const float*)d_in[2];
    const float* w1     = (const float*)d_in[3];
    const float* b1     = (const float*)d_in[4];
    const float* w2     = (const float*)d_in[5];
    const float* b2     = (const float*)d_in[6];
    float* out = (float*)d_out;

    float* wsf   = (float*)d_ws;
    float* stats = wsf;                       // 64 floats (8 b x 8 slots)
    float* ssum  = wsf + 64;                  // 1536 floats
    float* xcf   = wsf + 1600;                // 8*3*65536 raw xc (max/mean/min)
    float* muf   = xcf + (size_t)Bn * 3 * HWc;      // 8*3*60516
    float* ef2   = muf + (size_t)Bn * 3 * HPWPc;    // 8*3*60516

    hipMemsetAsync(d_ws, 0, 6400, stream);  // stats + ssum accumulators

    k1_stats<<<dim3(64, 8), 256, 0, stream>>>(x, mask, xcf, stats);
    k4_blur3<<<dim3(8, 8, 24), 256, 0, stream>>>(xcf, mask, stats, muf, ef2);
    k5_main<<<dim3(8, 8, 8), 256, 0, stream>>>(x, xcf, mask, stats, muf, ef2, ssum);
    k6_head<<<1, 512, 0, stream>>>(ssum, conv_w, w1, b1, w2, b2, out);
}

// Round 6
// 630.114 us; speedup vs baseline: 1.4889x; 1.0216x over previous
//
#include <hip/hip_runtime.h>
#include <cmath>

#define Bn   8
#define Cn   64
#define HWc  65536      // 256*256
#define HPc  246        // 256-11+1
#define HPWPc 60516     // 246*246
#define C1v  0.01f      // (0.01*10)^2
#define C2v  0.09f      // (0.03*10)^2
#define VPITCH 224      // vb5 row pitch (floats); channel-loop writes reach 219 -> 224 fits.
                        // LDS = 22176 (f-tiles) + 32*224*4 = 50848 B.

static __device__ __forceinline__ float4 f4z() { return make_float4(0.f, 0.f, 0.f, 0.f); }
static __device__ __forceinline__ float4 f4scale(float g, const float4 v) {
    return make_float4(g * v.x, g * v.y, g * v.z, g * v.w);
}
static __device__ __forceinline__ void f4add(float4& a, const float4 v) {
    a.x += v.x; a.y += v.y; a.z += v.z; a.w += v.w;
}
static __device__ __forceinline__ void f4fma(float4& a, const float4 u, const float4 v) {
    a.x = fmaf(u.x, v.x, a.x); a.y = fmaf(u.y, v.y, a.y);
    a.z = fmaf(u.z, v.z, a.z); a.w = fmaf(u.w, v.w, a.w);
}

// wave64 sum via DPP (VALU pipe, no LDS traffic). Result valid in lane 63.
static __device__ __forceinline__ float wave_sum64(float v) {
    v += __int_as_float(__builtin_amdgcn_update_dpp(0, __float_as_int(v), 0x111, 0xf, 0xf, true)); // row_shr:1
    v += __int_as_float(__builtin_amdgcn_update_dpp(0, __float_as_int(v), 0x112, 0xf, 0xf, true)); // row_shr:2
    v += __int_as_float(__builtin_amdgcn_update_dpp(0, __float_as_int(v), 0x114, 0xf, 0xf, true)); // row_shr:4
    v += __int_as_float(__builtin_amdgcn_update_dpp(0, __float_as_int(v), 0x118, 0xf, 0xf, true)); // row_shr:8
    v += __int_as_float(__builtin_amdgcn_update_dpp(0, __float_as_int(v), 0x142, 0xf, 0xf, true)); // row_bcast:15
    v += __int_as_float(__builtin_amdgcn_update_dpp(0, __float_as_int(v), 0x143, 0xf, 0xf, true)); // row_bcast:31
    return v;
}

// K1: channel max/mean/min (-> xcf planes, RAW) + masked stats atomics
__global__ __launch_bounds__(256) void k1_stats(const float* __restrict__ x, const int* __restrict__ mask,
                                                float* __restrict__ xcf, float* __restrict__ stats) {
    const int b = blockIdx.y;
    const int p0 = blockIdx.x * 1024 + threadIdx.x * 4;
    const float4* xp = (const float4*)(x + (size_t)b * Cn * HWc) + (p0 >> 2);
    float4 v = xp[0];
    float4 vmax = v, vmin = v, vsum = v;
#pragma unroll 4
    for (int c = 1; c < Cn; ++c) {
        float4 u = xp[(size_t)c * (HWc / 4)];
        vmax.x = fmaxf(vmax.x, u.x); vmax.y = fmaxf(vmax.y, u.y);
        vmax.z = fmaxf(vmax.z, u.z); vmax.w = fmaxf(vmax.w, u.w);
        vmin.x = fminf(vmin.x, u.x); vmin.y = fminf(vmin.y, u.y);
        vmin.z = fminf(vmin.z, u.z); vmin.w = fminf(vmin.w, u.w);
        vsum.x += u.x; vsum.y += u.y; vsum.z += u.z; vsum.w += u.w;
    }
    float4 vmean = make_float4(vsum.x * (1.f / 64.f), vsum.y * (1.f / 64.f),
                               vsum.z * (1.f / 64.f), vsum.w * (1.f / 64.f));
    *(float4*)(xcf + (size_t)(b * 3 + 0) * HWc + p0) = vmax;
    *(float4*)(xcf + (size_t)(b * 3 + 1) * HWc + p0) = vmean;
    *(float4*)(xcf + (size_t)(b * 3 + 2) * HWc + p0) = vmin;
    int4 mv = *(const int4*)(mask + (size_t)b * HWc + p0);
    float m0 = (float)mv.x, m1 = (float)mv.y, m2 = (float)mv.z, m3 = (float)mv.w;
    float r[7];
    r[0] = m0 + m1 + m2 + m3;
    r[1] = vmax.x * m0 + vmax.y * m1 + vmax.z * m2 + vmax.w * m3;
    r[2] = vmean.x * m0 + vmean.y * m1 + vmean.z * m2 + vmean.w * m3;
    r[3] = vmin.x * m0 + vmin.y * m1 + vmin.z * m2 + vmin.w * m3;
    r[4] = vmax.x * vmax.x * m0 + vmax.y * vmax.y * m1 + vmax.z * vmax.z * m2 + vmax.w * vmax.w * m3;
    r[5] = vmean.x * vmean.x * m0 + vmean.y * vmean.y * m1 + vmean.z * vmean.z * m2 + vmean.w * vmean.w * m3;
    r[6] = vmin.x * vmin.x * m0 + vmin.y * vmin.y * m1 + vmin.z * vmin.z * m2 + vmin.w * vmin.w * m3;
#pragma unroll
    for (int k = 0; k < 7; ++k) {
        float vv = wave_sum64(r[k]);
        if ((threadIdx.x & 63) == 63) atomicAdd(&stats[b * 8 + k], vv);
    }
}

// ---- K5 macro machinery (no local arrays; minimal persistent registers) ----
#define T(F,J,KK,V) h##F##_##J = fmaf(G##KK, (V), h##F##_##J);
#define TM0(F,V)  T(F,0,0,V)
#define TM1(F,V)  T(F,0,1,V) T(F,1,0,V)
#define TM2(F,V)  T(F,0,2,V) T(F,1,1,V) T(F,2,0,V)
#define TM3(F,V)  T(F,0,3,V) T(F,1,2,V) T(F,2,1,V) T(F,3,0,V)
#define TM4(F,V)  T(F,0,4,V) T(F,1,3,V) T(F,2,2,V) T(F,3,1,V)
#define TM5(F,V)  T(F,0,5,V) T(F,1,4,V) T(F,2,3,V) T(F,3,2,V)
#define TM6(F,V)  T(F,0,6,V) T(F,1,5,V) T(F,2,4,V) T(F,3,3,V)
#define TM7(F,V)  T(F,0,7,V) T(F,1,6,V) T(F,2,5,V) T(F,3,4,V)
#define TM8(F,V)  T(F,0,8,V) T(F,1,7,V) T(F,2,6,V) T(F,3,5,V)
#define TM9(F,V)  T(F,0,9,V) T(F,1,8,V) T(F,2,7,V) T(F,3,6,V)
#define TM10(F,V) T(F,0,10,V) T(F,1,9,V) T(F,2,8,V) T(F,3,7,V)
#define TM11(F,V) T(F,1,10,V) T(F,2,9,V) T(F,3,8,V)
#define TM12(F,V) T(F,2,10,V) T(F,3,9,V)
#define TM13(F,V) T(F,3,10,V)

#define DECLH(J) float h0_##J = 0.f, h1_##J = 0.f, h2_##J = 0.f, h3_##J = 0.f, h4_##J = 0.f;
// persistent per-thread constants: M = mu1, S = (s1 + C2) or +inf (invalid marker)
#define DECLJ(J) float M0_##J, M1_##J, M2_##J, S0_##J, S1_##J, S2_##J;

#define SSIMI(I,J,HV) { float am = M##I##_##J * m2; \
    float num = fmaf(2.f, am, C1v) * fmaf(2.f, (HV) - am, C2v); \
    float den = fmaf(M##I##_##J, M##I##_##J, c1m2) * (S##I##_##J + s2); \
    sa##I += num * __builtin_amdgcn_rcpf(den); }
#define SSIMJ(J) { float m2 = h0_##J; float m2sq = m2 * m2; \
    float c1m2 = C1v + m2sq; float s2 = h1_##J - m2sq; \
    SSIMI(0,J,h2_##J) SSIMI(1,J,h3_##J) SSIMI(2,J,h4_##J) }

// T14 async-STAGE split: XLOAD issues next channel's 12 global b128 loads into NAMED
// registers xv0..xv11 (no arrays -> no scratch); VCOMP consumes them.
#define XROW(K) { int gr = y0 + 2 * vrg + (K); gr = (gr > 255) ? 255 : gr; \
    xv##K = *(const float4*)(xp + gr * 256 + gcb); }
#define XLOAD(CC) do { if (vact) { \
    int cc = (CC); if (cc > Cn - 1) cc = Cn - 1; \
    const float* xp = xb + (size_t)cc * HWc; \
    XROW(0) XROW(1) XROW(2) XROW(3) XROW(4) XROW(5) \
    XROW(6) XROW(7) XROW(8) XROW(9) XROW(10) XROW(11) \
} } while (0)

#define VSTEP(K, DOA, DOB, GA, GB) { \
    float4 xv = xv##K; \
    const int ro = (2 * vrg + (K)) * 44 + vcolo; \
    float4 f0 = *(const float4*)&f0in[ro]; \
    float4 f1v = *(const float4*)&f1in[ro]; \
    float4 f2v = *(const float4*)&f2in[ro]; \
    if (DOA) { float4 tv = f4scale((GA), xv); f4add(xA0, tv); f4fma(xQ0, tv, xv); \
               f4fma(p00, tv, f0); f4fma(p10, tv, f1v); f4fma(p20, tv, f2v); } \
    if (DOB) { float4 tv = f4scale((GB), xv); f4add(xA1, tv); f4fma(xQ1, tv, xv); \
               f4fma(p01, tv, f0); f4fma(p11, tv, f1v); f4fma(p21, tv, f2v); } }

// VCOMP over STATIC __shared__ array name (R2 lesson: no runtime LDS pointer selects).
#define VCOMP(BUF) do { if (vact) { \
    float4 xA0 = f4z(), xQ0 = f4z(), p00 = f4z(), p10 = f4z(), p20 = f4z(); \
    float4 xA1 = f4z(), xQ1 = f4z(), p01 = f4z(), p11 = f4z(), p21 = f4z(); \
    VSTEP(0, 1, 0, G0, G0)  VSTEP(1, 1, 1, G1, G0)  VSTEP(2, 1, 1, G2, G1) \
    VSTEP(3, 1, 1, G3, G2)  VSTEP(4, 1, 1, G4, G3)  VSTEP(5, 1, 1, G5, G4) \
    VSTEP(6, 1, 1, G6, G5)  VSTEP(7, 1, 1, G7, G6)  VSTEP(8, 1, 1, G8, G7) \
    VSTEP(9, 1, 1, G9, G8)  VSTEP(10, 1, 1, G10, G9) VSTEP(11, 0, 1, G0, G10) \
    { float* dst = &BUF[(2 * vrg + 0) * VPITCH + vcolo * 5]; \
      *(float4*)&dst[0]  = make_float4(xA0.x, xQ0.x, p00.x, p10.x); \
      *(float4*)&dst[4]  = make_float4(p20.x, xA0.y, xQ0.y, p00.y); \
      *(float4*)&dst[8]  = make_float4(p10.y, p20.y, xA0.z, xQ0.z); \
      *(float4*)&dst[12] = make_float4(p00.z, p10.z, p20.z, xA0.w); \
      *(float4*)&dst[16] = make_float4(xQ0.w, p00.w, p10.w, p20.w); } \
    { float* dst = &BUF[(2 * vrg + 1) * VPITCH + vcolo * 5]; \
      *(float4*)&dst[0]  = make_float4(xA1.x, xQ1.x, p01.x, p11.x); \
      *(float4*)&dst[4]  = make_float4(p21.x, xA1.y, xQ1.y, p01.y); \
      *(float4*)&dst[8]  = make_float4(p11.y, p21.y, xA1.z, xQ1.z); \
      *(float4*)&dst[12] = make_float4(p01.z, p11.z, p21.z, xA1.w); \
      *(float4*)&dst[16] = make_float4(xQ1.w, p01.w, p11.w, p21.w); } \
} } while (0)

#define HORIZ(CC, BUF) do { \
    const float* src = &BUF[erow * VPITCH + ecg * 20]; \
    DECLH(0) DECLH(1) DECLH(2) DECLH(3) \
    float4 L0 = *(const float4*)(src + 0); \
    TM0(0, L0.x) TM0(1, L0.y) TM0(2, L0.z) TM0(3, L0.w) \
    float4 L1 = *(const float4*)(src + 4); \
    TM0(4, L1.x) TM1(0, L1.y) TM1(1, L1.z) TM1(2, L1.w) \
    float4 L2 = *(const float4*)(src + 8); \
    TM1(3, L2.x) TM1(4, L2.y) TM2(0, L2.z) TM2(1, L2.w) \
    float4 L3 = *(const float4*)(src + 12); \
    TM2(2, L3.x) TM2(3, L3.y) TM2(4, L3.z) TM3(0, L3.w) \
    float4 L4 = *(const float4*)(src + 16); \
    TM3(1, L4.x) TM3(2, L4.y) TM3(3, L4.z) TM3(4, L4.w) \
    float4 L5 = *(const float4*)(src + 20); \
    TM4(0, L5.x) TM4(1, L5.y) TM4(2, L5.z) TM4(3, L5.w) \
    float4 L6 = *(const float4*)(src + 24); \
    TM4(4, L6.x) TM5(0, L6.y) TM5(1, L6.z) TM5(2, L6.w) \
    float4 L7 = *(const float4*)(src + 28); \
    TM5(3, L7.x) TM5(4, L7.y) TM6(0, L7.z) TM6(1, L7.w) \
    float4 L8 = *(const float4*)(src + 32); \
    TM6(2, L8.x) TM6(3, L8.y) TM6(4, L8.z) TM7(0, L8.w) \
    float4 L9 = *(const float4*)(src + 36); \
    TM7(1, L9.x) TM7(2, L9.y) TM7(3, L9.z) TM7(4, L9.w) \
    float4 L10 = *(const float4*)(src + 40); \
    TM8(0, L10.x) TM8(1, L10.y) TM8(2, L10.z) TM8(3, L10.w) \
    float4 L11 = *(const float4*)(src + 44); \
    TM8(4, L11.x) TM9(0, L11.y) TM9(1, L11.z) TM9(2, L11.w) \
    float4 L12 = *(const float4*)(src + 48); \
    TM9(3, L12.x) TM9(4, L12.y) TM10(0, L12.z) TM10(1, L12.w) \
    float4 L13 = *(const float4*)(src + 52); \
    TM10(2, L13.x) TM10(3, L13.y) TM10(4, L13.z) TM11(0, L13.w) \
    float4 L14 = *(const float4*)(src + 56); \
    TM11(1, L14.x) TM11(2, L14.y) TM11(3, L14.z) TM11(4, L14.w) \
    float4 L15 = *(const float4*)(src + 60); \
    TM12(0, L15.x) TM12(1, L15.y) TM12(2, L15.z) TM12(3, L15.w) \
    float4 L16 = *(const float4*)(src + 64); \
    TM12(4, L16.x) TM13(0, L16.y) TM13(1, L16.z) TM13(2, L16.w) \
    float4 L17 = *(const float4*)(src + 68); \
    TM13(3, L17.x) TM13(4, L17.y) \
    float sa0 = 0.f, sa1 = 0.f, sa2 = 0.f; \
    SSIMJ(0) SSIMJ(1) SSIMJ(2) SSIMJ(3) \
    sa0 = wave_sum64(sa0); \
    sa1 = wave_sum64(sa1); \
    sa2 = wave_sum64(sa2); \
    if ((t & 63) == 63) { \
        atomicAdd(&ssum[(b * 3 + 0) * 64 + (CC)], sa0); \
        atomicAdd(&ssum[(b * 3 + 1) * 64 + (CC)], sa1); \
        atomicAdd(&ssum[(b * 3 + 2) * 64 + (CC)], sa2); \
    } \
} while (0)

// ---- Fused k4: blur(f) and blur(f^2) for plane SRC, results -> M/S registers ----
// Replicates the old k4_blur3 vert (av/ab, k ascending) and horiz (m/j loops) FMA
// order exactly -> bit-identical M (=muf) and e2 (=ef2) values.
#define FSTEP(SRC, K, DOA, DOB, GA, GB) { \
    float4 ff = *(const float4*)&SRC[(2 * vrg + (K)) * 44 + vcolo]; \
    if (DOA) { float4 tv = f4scale((GA), ff); f4add(av0, tv); f4fma(ab0, tv, ff); } \
    if (DOB) { float4 tv = f4scale((GB), ff); f4add(av1, tv); f4fma(ab1, tv, ff); } }

#define VERTF(SRC) do { if (vact) { \
    float4 av0 = f4z(), ab0 = f4z(), av1 = f4z(), ab1 = f4z(); \
    FSTEP(SRC, 0, 1, 0, G0, G0)  FSTEP(SRC, 1, 1, 1, G1, G0)  FSTEP(SRC, 2, 1, 1, G2, G1) \
    FSTEP(SRC, 3, 1, 1, G3, G2)  FSTEP(SRC, 4, 1, 1, G4, G3)  FSTEP(SRC, 5, 1, 1, G5, G4) \
    FSTEP(SRC, 6, 1, 1, G6, G5)  FSTEP(SRC, 7, 1, 1, G7, G6)  FSTEP(SRC, 8, 1, 1, G8, G7) \
    FSTEP(SRC, 9, 1, 1, G9, G8)  FSTEP(SRC, 10, 1, 1, G10, G9) FSTEP(SRC, 11, 0, 1, G0, G10) \
    { float* dst = &vb5[(2 * vrg + 0) * VPITCH + vcolo * 2]; \
      *(float4*)&dst[0] = make_float4(av0.x, ab0.x, av0.y, ab0.y); \
      *(float4*)&dst[4] = make_float4(av0.z, ab0.z, av0.w, ab0.w); } \
    { float* dst = &vb5[(2 * vrg + 1) * VPITCH + vcolo * 2]; \
      *(float4*)&dst[0] = make_float4(av1.x, ab1.x, av1.y, ab1.y); \
      *(float4*)&dst[4] = make_float4(av1.z, ab1.z, av1.w, ab1.w); } \
} } while (0)

#define HSETJ(I, J, AM, AE) { bool vld = (oy < HPc) && (ox0 + (J) < HPc); \
    M##I##_##J = vld ? (AM) : 0.f; \
    S##I##_##J = vld ? (((AE) - (AM) * (AM)) + C2v) : __builtin_inff(); }

#define HORIZF(I) do { \
    const float* hsrc = &vb5[erow * VPITCH + ecg * 8]; \
    float a00 = 0.f, a01 = 0.f, a02 = 0.f, a03 = 0.f; \
    float a10 = 0.f, a11 = 0.f, a12 = 0.f, a13 = 0.f; \
    _Pragma("unroll") \
    for (int m = 0; m < 14; ++m) { \
        float v0 = hsrc[m * 2 + 0]; \
        float v1 = hsrc[m * 2 + 1]; \
        _Pragma("unroll") \
        for (int j = 0; j < 4; ++j) { \
            const int kk = m - j; \
            if (kk >= 0 && kk <= 10) { \
                float g = gwA[kk]; \
                if (j == 0) { a00 = fmaf(g, v0, a00); a10 = fmaf(g, v1, a10); } \
                if (j == 1) { a01 = fmaf(g, v0, a01); a11 = fmaf(g, v1, a11); } \
                if (j == 2) { a02 = fmaf(g, v0, a02); a12 = fmaf(g, v1, a12); } \
                if (j == 3) { a03 = fmaf(g, v0, a03); a13 = fmaf(g, v1, a13); } \
            } \
        } \
    } \
    HSETJ(I, 0, a00, a10) HSETJ(I, 1, a01, a11) HSETJ(I, 2, a02, a12) HSETJ(I, 3, a03, a13) \
} while (0)

// K5: per (b, 32x32 tile): xf tiles staged in LDS once; fused k4 (mu_f/ef2 blur ->
// M/S registers, no global round-trip, no separate kernel); then 64-channel loop:
// VCOMP(c) [consumes prefetched xv regs]; XLOAD(c+1); bar; HORIZ(c); bar.
// __launch_bounds__(256,2): 128-VGPR budget — (256,3) spills.
// LDS = 22176 + 28672 = 50848 B.
// R0-R4 evidence trail: bank-conflict counter partially structural (R4: 5.1e7->3.7e7);
// barrier count not the bottleneck (R3); T14 prefetch +10% (R4).
__global__ __launch_bounds__(256, 2) void k5_main(const float* __restrict__ x, const float* __restrict__ xc,
                                                  const int* __restrict__ mask, const float* __restrict__ stats,
                                                  float* __restrict__ ssum) {
    __shared__ __align__(16) float f0in[42 * 44];
    __shared__ __align__(16) float f1in[42 * 44];
    __shared__ __align__(16) float f2in[42 * 44];
    __shared__ __align__(16) float vb5[32 * VPITCH];
    const int t = threadIdx.x;
    const int b = blockIdx.z;
    const int y0 = blockIdx.y * 32, x0 = blockIdx.x * 32;
    // gauss weights as named scalars (same numerics as the original gauss11)
    const double e0 = exp(-25.0 / 4.5), e1 = exp(-16.0 / 4.5), e2d = exp(-9.0 / 4.5),
                 e3 = exp(-4.0 / 4.5), e4 = exp(-1.0 / 4.5);
    const double sg = 1.0 + 2.0 * (e0 + e1 + e2d + e3 + e4);
    const float G0 = (float)(e0 / sg), G1 = (float)(e1 / sg), G2 = (float)(e2d / sg),
                G3 = (float)(e3 / sg), G4 = (float)(e4 / sg), G5 = (float)(1.0 / sg);
    const float G6 = G4, G7 = G3, G8 = G2, G9 = G1, G10 = G0;
    const float gwA[11] = { G0, G1, G2, G3, G4, G5, G6, G7, G8, G9, G10 };
    // per-(b,i) normalization constants
    const float nst = stats[b * 8 + 0];
    const float s1a = stats[b * 8 + 1], s2a = stats[b * 8 + 4];
    const float s1b = stats[b * 8 + 2], s2b = stats[b * 8 + 5];
    const float s1c = stats[b * 8 + 3], s2c = stats[b * 8 + 6];
    const float mean0 = s1a / nst, rstd0 = rsqrtf((s2a - s1a * s1a / nst) / (nst - 1.0f));
    const float mean1 = s1b / nst, rstd1 = rsqrtf((s2b - s1b * s1b / nst) / (nst - 1.0f));
    const float mean2 = s1c / nst, rstd2 = rsqrtf((s2c - s1c * s1c / nst) / (nst - 1.0f));
    // stage normalized xf tiles (once per block)
    for (int q = t; q < 42 * 11; q += 256) {
        int row = q / 11, cg = q % 11;
        int gr = min(y0 + row, 255), gc = min(x0 + cg * 4, 252);
        int go = gr * 256 + gc;
        int lo = row * 44 + cg * 4;
        int4 mv = *(const int4*)(mask + (size_t)b * HWc + go);
        float m0 = (float)mv.x, m1 = (float)mv.y, m2 = (float)mv.z, m3 = (float)mv.w;
        float4 v0 = *(const float4*)(xc + (size_t)(b * 3 + 0) * HWc + go);
        v0.x = (v0.x - mean0) * rstd0 * m0; v0.y = (v0.y - mean0) * rstd0 * m1;
        v0.z = (v0.z - mean0) * rstd0 * m2; v0.w = (v0.w - mean0) * rstd0 * m3;
        *(float4*)&f0in[lo] = v0;
        float4 v1 = *(const float4*)(xc + (size_t)(b * 3 + 1) * HWc + go);
        v1.x = (v1.x - mean1) * rstd1 * m0; v1.y = (v1.y - mean1) * rstd1 * m1;
        v1.z = (v1.z - mean1) * rstd1 * m2; v1.w = (v1.w - mean1) * rstd1 * m3;
        *(float4*)&f1in[lo] = v1;
        float4 v2 = *(const float4*)(xc + (size_t)(b * 3 + 2) * HWc + go);
        v2.x = (v2.x - mean2) * rstd2 * m0; v2.y = (v2.y - mean2) * rstd2 * m1;
        v2.z = (v2.z - mean2) * rstd2 * m2; v2.w = (v2.w - mean2) * rstd2 * m3;
        *(float4*)&f2in[lo] = v2;
    }
    // per-thread c-independent eval constants
    const int erow = t >> 3, ecg = t & 7;
    const int oy = y0 + erow;
    const int ox0 = x0 + ecg * 4;
    DECLJ(0) DECLJ(1) DECLJ(2) DECLJ(3)
    const float* xb = x + (size_t)b * Cn * HWc;
    const int vrg = t / 11, vcg = t % 11, vcolo = vcg * 4;
    const int gcb = min(x0 + vcolo, 252);
    const bool vact = (t < 176);
    float4 xv0, xv1, xv2, xv3, xv4, xv5, xv6, xv7, xv8, xv9, xv10, xv11;

    __syncthreads();           // f-tiles staged
    // fused k4: 3 planes of {vert blur -> vb5 -> horiz blur -> M/S regs}
    VERTF(f0in);
    __syncthreads();
    HORIZF(0);
    __syncthreads();           // vb5 consumed
    VERTF(f1in);
    __syncthreads();
    HORIZF(1);
    __syncthreads();
    VERTF(f2in);
    __syncthreads();
    XLOAD(0);                  // prefetch channel 0; in flight across HORIZF(2)+bar
    HORIZF(2);
    __syncthreads();           // vb5 consumed; channel loop may overwrite
#pragma unroll 1
    for (int c = 0; c < Cn; ++c) {
        VCOMP(vb5);            // consume xv(c); vert compute + LDS write
        XLOAD(c + 1);          // issue next channel's loads (clamped at c=63: redundant, L2-hot)
        __syncthreads();       // vb5 written
        HORIZ(c, vb5);         // ~1200+ VALU cycles/SIMD hide the in-flight loads
        __syncthreads();       // vb5 consumed before next VCOMP overwrites
    }
}

// K6: normalize ssim sums -> ssim_info output; conv3 over C + MLP head -> h output
__global__ __launch_bounds__(512) void k6_head(const float* __restrict__ ssum, const float* __restrict__ cw,
                                               const float* __restrict__ w1, const float* __restrict__ b1,
                                               const float* __restrict__ w2, const float* __restrict__ b2,
                                               float* __restrict__ out) {
    __shared__ float si[1536];
    __shared__ float h0[512];
    __shared__ float h1[512];
    const int t = threadIdx.x;
    const float inv = 1.0f / (float)HPWPc;
    for (int idx = t; idx < 1536; idx += 512) {
        float v = ssum[idx] * inv;
        si[idx] = v;
        out[512 + idx] = v;
    }
    __syncthreads();
    const int b = t >> 6, y = t & 63;
    float acc = 0.f;
#pragma unroll
    for (int i = 0; i < 3; ++i) {
#pragma unroll
        for (int kh = 0; kh < 3; ++kh) {
            int yy = y + kh - 1;
            if (yy >= 0 && yy < 64) acc = fmaf(si[(b * 3 + i) * 64 + yy], cw[i * 3 + kh], acc);
        }
    }
    h0[t] = fmaxf(acc, 0.f);
    __syncthreads();
    float a1 = b1[y];
    for (int c = 0; c < 64; ++c) a1 = fmaf(h0[(b << 6) + c], w1[(y << 6) + c], a1);
    h1[t] = fmaxf(a1, 0.f);
    __syncthreads();
    float a2 = b2[y];
    for (int c = 0; c < 64; ++c) a2 = fmaf(h1[(b << 6) + c], w2[(y << 6) + c], a2);
    out[t] = 1.f / (1.f + expf(-a2));
}

extern "C" void kernel_launch(void* const* d_in, const int* in_sizes, int n_in,
                              void* d_out, int out_size, void* d_ws, size_t ws_size,
                              hipStream_t stream) {
    const float* x      = (const float*)d_in[0];
    const int*   mask   = (const int*)d_in[1];
    const float* conv_w = (const float*)d_in[2];
    const float* w1     = (const float*)d_in[3];
    const float* b1     = (const float*)d_in[4];
    const float* w2     = (const float*)d_in[5];
    const float* b2     = (const float*)d_in[6];
    float* out = (float*)d_out;

    float* wsf   = (float*)d_ws;
    float* stats = wsf;                       // 64 floats (8 b x 8 slots)
    float* ssum  = wsf + 64;                  // 1536 floats
    float* xcf   = wsf + 1600;                // 8*3*65536 raw xc (max/mean/min)

    hipMemsetAsync(d_ws, 0, 6400, stream);  // stats + ssum accumulators

    k1_stats<<<dim3(64, 8), 256, 0, stream>>>(x, mask, xcf, stats);
    k5_main<<<dim3(8, 8, 8), 256, 0, stream>>>(x, xcf, mask, stats, ssum);
    k6_head<<<1, 512, 0, stream>>>(ssum, conv_w, w1, b1, w2, b2, out);
}

// Round 7
// 622.421 us; speedup vs baseline: 1.5073x; 1.0124x over previous
//
#include <hip/hip_runtime.h>
#include <cmath>

#define Bn   8
#define Cn   64
#define HWc  65536      // 256*256
#define HPc  246        // 256-11+1
#define HPWPc 60516     // 246*246
#define C1v  0.01f      // (0.01*10)^2
#define C2v  0.09f      // (0.03*10)^2
#define VPITCH 224      // vb5 row pitch (floats); channel-loop writes reach 219 -> 224 fits.
                        // LDS = 22176 (f-tiles) + 32*224*4 = 50848 B.

static __device__ __forceinline__ float4 f4z() { return make_float4(0.f, 0.f, 0.f, 0.f); }
static __device__ __forceinline__ float4 f4scale(float g, const float4 v) {
    return make_float4(g * v.x, g * v.y, g * v.z, g * v.w);
}
static __device__ __forceinline__ void f4add(float4& a, const float4 v) {
    a.x += v.x; a.y += v.y; a.z += v.z; a.w += v.w;
}
static __device__ __forceinline__ void f4fma(float4& a, const float4 u, const float4 v) {
    a.x = fmaf(u.x, v.x, a.x); a.y = fmaf(u.y, v.y, a.y);
    a.z = fmaf(u.z, v.z, a.z); a.w = fmaf(u.w, v.w, a.w);
}

// wave64 sum via DPP (VALU pipe, no LDS traffic). Result valid in lane 63.
static __device__ __forceinline__ float wave_sum64(float v) {
    v += __int_as_float(__builtin_amdgcn_update_dpp(0, __float_as_int(v), 0x111, 0xf, 0xf, true)); // row_shr:1
    v += __int_as_float(__builtin_amdgcn_update_dpp(0, __float_as_int(v), 0x112, 0xf, 0xf, true)); // row_shr:2
    v += __int_as_float(__builtin_amdgcn_update_dpp(0, __float_as_int(v), 0x114, 0xf, 0xf, true)); // row_shr:4
    v += __int_as_float(__builtin_amdgcn_update_dpp(0, __float_as_int(v), 0x118, 0xf, 0xf, true)); // row_shr:8
    v += __int_as_float(__builtin_amdgcn_update_dpp(0, __float_as_int(v), 0x142, 0xf, 0xf, true)); // row_bcast:15
    v += __int_as_float(__builtin_amdgcn_update_dpp(0, __float_as_int(v), 0x143, 0xf, 0xf, true)); // row_bcast:31
    return v;
}

// K1: channel max/mean/min (-> xcf planes, RAW) + masked stats atomics.
// R6 post-mortem: non-k5 time has been ~263 µs constant all session; k1 is the only
// candidate big enough. Diagnosis: 8 waves/CU (grid-fixed) x unroll-4 = only ~4 loads
// in flight -> ~16 serialized ~900-cyc HBM batches/wave. Fix: unroll 16 (ILP, not TLP;
// total waves are fixed by the 1-thread-per-pixel-quad decomposition). FP chain order
// unchanged (no fast-math reassociation at -O3) -> bit-exact.
__global__ __launch_bounds__(256) void k1_stats(const float* __restrict__ x, const int* __restrict__ mask,
                                                float* __restrict__ xcf, float* __restrict__ stats) {
    const int b = blockIdx.y;
    const int p0 = blockIdx.x * 1024 + threadIdx.x * 4;
    const float4* xp = (const float4*)(x + (size_t)b * Cn * HWc) + (p0 >> 2);
    int4 mv = *(const int4*)(mask + (size_t)b * HWc + p0);   // issue early; consumed after loop
    float4 v = xp[0];
    float4 vmax = v, vmin = v, vsum = v;
#pragma unroll 16
    for (int c = 1; c < Cn; ++c) {
        float4 u = xp[(size_t)c * (HWc / 4)];
        vmax.x = fmaxf(vmax.x, u.x); vmax.y = fmaxf(vmax.y, u.y);
        vmax.z = fmaxf(vmax.z, u.z); vmax.w = fmaxf(vmax.w, u.w);
        vmin.x = fminf(vmin.x, u.x); vmin.y = fminf(vmin.y, u.y);
        vmin.z = fminf(vmin.z, u.z); vmin.w = fminf(vmin.w, u.w);
        vsum.x += u.x; vsum.y += u.y; vsum.z += u.z; vsum.w += u.w;
    }
    float4 vmean = make_float4(vsum.x * (1.f / 64.f), vsum.y * (1.f / 64.f),
                               vsum.z * (1.f / 64.f), vsum.w * (1.f / 64.f));
    *(float4*)(xcf + (size_t)(b * 3 + 0) * HWc + p0) = vmax;
    *(float4*)(xcf + (size_t)(b * 3 + 1) * HWc + p0) = vmean;
    *(float4*)(xcf + (size_t)(b * 3 + 2) * HWc + p0) = vmin;
    float m0 = (float)mv.x, m1 = (float)mv.y, m2 = (float)mv.z, m3 = (float)mv.w;
    float r[7];
    r[0] = m0 + m1 + m2 + m3;
    r[1] = vmax.x * m0 + vmax.y * m1 + vmax.z * m2 + vmax.w * m3;
    r[2] = vmean.x * m0 + vmean.y * m1 + vmean.z * m2 + vmean.w * m3;
    r[3] = vmin.x * m0 + vmin.y * m1 + vmin.z * m2 + vmin.w * m3;
    r[4] = vmax.x * vmax.x * m0 + vmax.y * vmax.y * m1 + vmax.z * vmax.z * m2 + vmax.w * vmax.w * m3;
    r[5] = vmean.x * vmean.x * m0 + vmean.y * vmean.y * m1 + vmean.z * vmean.z * m2 + vmean.w * vmean.w * m3;
    r[6] = vmin.x * vmin.x * m0 + vmin.y * vmin.y * m1 + vmin.z * vmin.z * m2 + vmin.w * vmin.w * m3;
#pragma unroll
    for (int k = 0; k < 7; ++k) {
        float vv = wave_sum64(r[k]);
        if ((threadIdx.x & 63) == 63) atomicAdd(&stats[b * 8 + k], vv);
    }
}

// ---- K5 macro machinery (no local arrays; minimal persistent registers) ----
#define T(F,J,KK,V) h##F##_##J = fmaf(G##KK, (V), h##F##_##J);
#define TM0(F,V)  T(F,0,0,V)
#define TM1(F,V)  T(F,0,1,V) T(F,1,0,V)
#define TM2(F,V)  T(F,0,2,V) T(F,1,1,V) T(F,2,0,V)
#define TM3(F,V)  T(F,0,3,V) T(F,1,2,V) T(F,2,1,V) T(F,3,0,V)
#define TM4(F,V)  T(F,0,4,V) T(F,1,3,V) T(F,2,2,V) T(F,3,1,V)
#define TM5(F,V)  T(F,0,5,V) T(F,1,4,V) T(F,2,3,V) T(F,3,2,V)
#define TM6(F,V)  T(F,0,6,V) T(F,1,5,V) T(F,2,4,V) T(F,3,3,V)
#define TM7(F,V)  T(F,0,7,V) T(F,1,6,V) T(F,2,5,V) T(F,3,4,V)
#define TM8(F,V)  T(F,0,8,V) T(F,1,7,V) T(F,2,6,V) T(F,3,5,V)
#define TM9(F,V)  T(F,0,9,V) T(F,1,8,V) T(F,2,7,V) T(F,3,6,V)
#define TM10(F,V) T(F,0,10,V) T(F,1,9,V) T(F,2,8,V) T(F,3,7,V)
#define TM11(F,V) T(F,1,10,V) T(F,2,9,V) T(F,3,8,V)
#define TM12(F,V) T(F,2,10,V) T(F,3,9,V)
#define TM13(F,V) T(F,3,10,V)

#define DECLH(J) float h0_##J = 0.f, h1_##J = 0.f, h2_##J = 0.f, h3_##J = 0.f, h4_##J = 0.f;
// persistent per-thread constants: M = mu1, S = (s1 + C2) or +inf (invalid marker)
#define DECLJ(J) float M0_##J, M1_##J, M2_##J, S0_##J, S1_##J, S2_##J;

#define SSIMI(I,J,HV) { float am = M##I##_##J * m2; \
    float num = fmaf(2.f, am, C1v) * fmaf(2.f, (HV) - am, C2v); \
    float den = fmaf(M##I##_##J, M##I##_##J, c1m2) * (S##I##_##J + s2); \
    sa##I += num * __builtin_amdgcn_rcpf(den); }
#define SSIMJ(J) { float m2 = h0_##J; float m2sq = m2 * m2; \
    float c1m2 = C1v + m2sq; float s2 = h1_##J - m2sq; \
    SSIMI(0,J,h2_##J) SSIMI(1,J,h3_##J) SSIMI(2,J,h4_##J) }

// T14 async-STAGE split: XLOAD issues next channel's 12 global b128 loads into NAMED
// registers xv0..xv11 (no arrays -> no scratch); VCOMP consumes them.
#define XROW(K) { int gr = y0 + 2 * vrg + (K); gr = (gr > 255) ? 255 : gr; \
    xv##K = *(const float4*)(xp + gr * 256 + gcb); }
#define XLOAD(CC) do { if (vact) { \
    int cc = (CC); if (cc > Cn - 1) cc = Cn - 1; \
    const float* xp = xb + (size_t)cc * HWc; \
    XROW(0) XROW(1) XROW(2) XROW(3) XROW(4) XROW(5) \
    XROW(6) XROW(7) XROW(8) XROW(9) XROW(10) XROW(11) \
} } while (0)

#define VSTEP(K, DOA, DOB, GA, GB) { \
    float4 xv = xv##K; \
    const int ro = (2 * vrg + (K)) * 44 + vcolo; \
    float4 f0 = *(const float4*)&f0in[ro]; \
    float4 f1v = *(const float4*)&f1in[ro]; \
    float4 f2v = *(const float4*)&f2in[ro]; \
    if (DOA) { float4 tv = f4scale((GA), xv); f4add(xA0, tv); f4fma(xQ0, tv, xv); \
               f4fma(p00, tv, f0); f4fma(p10, tv, f1v); f4fma(p20, tv, f2v); } \
    if (DOB) { float4 tv = f4scale((GB), xv); f4add(xA1, tv); f4fma(xQ1, tv, xv); \
               f4fma(p01, tv, f0); f4fma(p11, tv, f1v); f4fma(p21, tv, f2v); } }

// VCOMP over STATIC __shared__ array name (R2 lesson: no runtime LDS pointer selects).
#define VCOMP(BUF) do { if (vact) { \
    float4 xA0 = f4z(), xQ0 = f4z(), p00 = f4z(), p10 = f4z(), p20 = f4z(); \
    float4 xA1 = f4z(), xQ1 = f4z(), p01 = f4z(), p11 = f4z(), p21 = f4z(); \
    VSTEP(0, 1, 0, G0, G0)  VSTEP(1, 1, 1, G1, G0)  VSTEP(2, 1, 1, G2, G1) \
    VSTEP(3, 1, 1, G3, G2)  VSTEP(4, 1, 1, G4, G3)  VSTEP(5, 1, 1, G5, G4) \
    VSTEP(6, 1, 1, G6, G5)  VSTEP(7, 1, 1, G7, G6)  VSTEP(8, 1, 1, G8, G7) \
    VSTEP(9, 1, 1, G9, G8)  VSTEP(10, 1, 1, G10, G9) VSTEP(11, 0, 1, G0, G10) \
    { float* dst = &BUF[(2 * vrg + 0) * VPITCH + vcolo * 5]; \
      *(float4*)&dst[0]  = make_float4(xA0.x, xQ0.x, p00.x, p10.x); \
      *(float4*)&dst[4]  = make_float4(p20.x, xA0.y, xQ0.y, p00.y); \
      *(float4*)&dst[8]  = make_float4(p10.y, p20.y, xA0.z, xQ0.z); \
      *(float4*)&dst[12] = make_float4(p00.z, p10.z, p20.z, xA0.w); \
      *(float4*)&dst[16] = make_float4(xQ0.w, p00.w, p10.w, p20.w); } \
    { float* dst = &BUF[(2 * vrg + 1) * VPITCH + vcolo * 5]; \
      *(float4*)&dst[0]  = make_float4(xA1.x, xQ1.x, p01.x, p11.x); \
      *(float4*)&dst[4]  = make_float4(p21.x, xA1.y, xQ1.y, p01.y); \
      *(float4*)&dst[8]  = make_float4(p11.y, p21.y, xA1.z, xQ1.z); \
      *(float4*)&dst[12] = make_float4(p01.z, p11.z, p21.z, xA1.w); \
      *(float4*)&dst[16] = make_float4(xQ1.w, p01.w, p11.w, p21.w); } \
} } while (0)

#define HORIZ(CC, BUF) do { \
    const float* src = &BUF[erow * VPITCH + ecg * 20]; \
    DECLH(0) DECLH(1) DECLH(2) DECLH(3) \
    float4 L0 = *(const float4*)(src + 0); \
    TM0(0, L0.x) TM0(1, L0.y) TM0(2, L0.z) TM0(3, L0.w) \
    float4 L1 = *(const float4*)(src + 4); \
    TM0(4, L1.x) TM1(0, L1.y) TM1(1, L1.z) TM1(2, L1.w) \
    float4 L2 = *(const float4*)(src + 8); \
    TM1(3, L2.x) TM1(4, L2.y) TM2(0, L2.z) TM2(1, L2.w) \
    float4 L3 = *(const float4*)(src + 12); \
    TM2(2, L3.x) TM2(3, L3.y) TM2(4, L3.z) TM3(0, L3.w) \
    float4 L4 = *(const float4*)(src + 16); \
    TM3(1, L4.x) TM3(2, L4.y) TM3(3, L4.z) TM3(4, L4.w) \
    float4 L5 = *(const float4*)(src + 20); \
    TM4(0, L5.x) TM4(1, L5.y) TM4(2, L5.z) TM4(3, L5.w) \
    float4 L6 = *(const float4*)(src + 24); \
    TM4(4, L6.x) TM5(0, L6.y) TM5(1, L6.z) TM5(2, L6.w) \
    float4 L7 = *(const float4*)(src + 28); \
    TM5(3, L7.x) TM5(4, L7.y) TM6(0, L7.z) TM6(1, L7.w) \
    float4 L8 = *(const float4*)(src + 32); \
    TM6(2, L8.x) TM6(3, L8.y) TM6(4, L8.z) TM7(0, L8.w) \
    float4 L9 = *(const float4*)(src + 36); \
    TM7(1, L9.x) TM7(2, L9.y) TM7(3, L9.z) TM7(4, L9.w) \
    float4 L10 = *(const float4*)(src + 40); \
    TM8(0, L10.x) TM8(1, L10.y) TM8(2, L10.z) TM8(3, L10.w) \
    float4 L11 = *(const float4*)(src + 44); \
    TM8(4, L11.x) TM9(0, L11.y) TM9(1, L11.z) TM9(2, L11.w) \
    float4 L12 = *(const float4*)(src + 48); \
    TM9(3, L12.x) TM9(4, L12.y) TM10(0, L12.z) TM10(1, L12.w) \
    float4 L13 = *(const float4*)(src + 52); \
    TM10(2, L13.x) TM10(3, L13.y) TM10(4, L13.z) TM11(0, L13.w) \
    float4 L14 = *(const float4*)(src + 56); \
    TM11(1, L14.x) TM11(2, L14.y) TM11(3, L14.z) TM11(4, L14.w) \
    float4 L15 = *(const float4*)(src + 60); \
    TM12(0, L15.x) TM12(1, L15.y) TM12(2, L15.z) TM12(3, L15.w) \
    float4 L16 = *(const float4*)(src + 64); \
    TM12(4, L16.x) TM13(0, L16.y) TM13(1, L16.z) TM13(2, L16.w) \
    float4 L17 = *(const float4*)(src + 68); \
    TM13(3, L17.x) TM13(4, L17.y) \
    float sa0 = 0.f, sa1 = 0.f, sa2 = 0.f; \
    SSIMJ(0) SSIMJ(1) SSIMJ(2) SSIMJ(3) \
    sa0 = wave_sum64(sa0); \
    sa1 = wave_sum64(sa1); \
    sa2 = wave_sum64(sa2); \
    if ((t & 63) == 63) { \
        atomicAdd(&ssum[(b * 3 + 0) * 64 + (CC)], sa0); \
        atomicAdd(&ssum[(b * 3 + 1) * 64 + (CC)], sa1); \
        atomicAdd(&ssum[(b * 3 + 2) * 64 + (CC)], sa2); \
    } \
} while (0)

// ---- Fused k4: blur(f) and blur(f^2) for plane SRC, results -> M/S registers ----
// Replicates the old k4_blur3 vert (av/ab, k ascending) and horiz (m/j loops) FMA
// order exactly -> bit-identical M (=muf) and e2 (=ef2) values.
#define FSTEP(SRC, K, DOA, DOB, GA, GB) { \
    float4 ff = *(const float4*)&SRC[(2 * vrg + (K)) * 44 + vcolo]; \
    if (DOA) { float4 tv = f4scale((GA), ff); f4add(av0, tv); f4fma(ab0, tv, ff); } \
    if (DOB) { float4 tv = f4scale((GB), ff); f4add(av1, tv); f4fma(ab1, tv, ff); } }

#define VERTF(SRC) do { if (vact) { \
    float4 av0 = f4z(), ab0 = f4z(), av1 = f4z(), ab1 = f4z(); \
    FSTEP(SRC, 0, 1, 0, G0, G0)  FSTEP(SRC, 1, 1, 1, G1, G0)  FSTEP(SRC, 2, 1, 1, G2, G1) \
    FSTEP(SRC, 3, 1, 1, G3, G2)  FSTEP(SRC, 4, 1, 1, G4, G3)  FSTEP(SRC, 5, 1, 1, G5, G4) \
    FSTEP(SRC, 6, 1, 1, G6, G5)  FSTEP(SRC, 7, 1, 1, G7, G6)  FSTEP(SRC, 8, 1, 1, G8, G7) \
    FSTEP(SRC, 9, 1, 1, G9, G8)  FSTEP(SRC, 10, 1, 1, G10, G9) FSTEP(SRC, 11, 0, 1, G0, G10) \
    { float* dst = &vb5[(2 * vrg + 0) * VPITCH + vcolo * 2]; \
      *(float4*)&dst[0] = make_float4(av0.x, ab0.x, av0.y, ab0.y); \
      *(float4*)&dst[4] = make_float4(av0.z, ab0.z, av0.w, ab0.w); } \
    { float* dst = &vb5[(2 * vrg + 1) * VPITCH + vcolo * 2]; \
      *(float4*)&dst[0] = make_float4(av1.x, ab1.x, av1.y, ab1.y); \
      *(float4*)&dst[4] = make_float4(av1.z, ab1.z, av1.w, ab1.w); } \
} } while (0)

#define HSETJ(I, J, AM, AE) { bool vld = (oy < HPc) && (ox0 + (J) < HPc); \
    M##I##_##J = vld ? (AM) : 0.f; \
    S##I##_##J = vld ? (((AE) - (AM) * (AM)) + C2v) : __builtin_inff(); }

#define HORIZF(I) do { \
    const float* hsrc = &vb5[erow * VPITCH + ecg * 8]; \
    float a00 = 0.f, a01 = 0.f, a02 = 0.f, a03 = 0.f; \
    float a10 = 0.f, a11 = 0.f, a12 = 0.f, a13 = 0.f; \
    _Pragma("unroll") \
    for (int m = 0; m < 14; ++m) { \
        float v0 = hsrc[m * 2 + 0]; \
        float v1 = hsrc[m * 2 + 1]; \
        _Pragma("unroll") \
        for (int j = 0; j < 4; ++j) { \
            const int kk = m - j; \
            if (kk >= 0 && kk <= 10) { \
                float g = gwA[kk]; \
                if (j == 0) { a00 = fmaf(g, v0, a00); a10 = fmaf(g, v1, a10); } \
                if (j == 1) { a01 = fmaf(g, v0, a01); a11 = fmaf(g, v1, a11); } \
                if (j == 2) { a02 = fmaf(g, v0, a02); a12 = fmaf(g, v1, a12); } \
                if (j == 3) { a03 = fmaf(g, v0, a03); a13 = fmaf(g, v1, a13); } \
            } \
        } \
    } \
    HSETJ(I, 0, a00, a10) HSETJ(I, 1, a01, a11) HSETJ(I, 2, a02, a12) HSETJ(I, 3, a03, a13) \
} while (0)

// K5: per (b, 32x32 tile): xf tiles staged in LDS once; fused k4 (mu_f/ef2 blur ->
// M/S registers, no global round-trip, no separate kernel); then 64-channel loop:
// VCOMP(c) [consumes prefetched xv regs]; XLOAD(c+1); bar; HORIZ(c); bar.
// __launch_bounds__(256,2): 128-VGPR budget — (256,3) spills.
// LDS = 22176 + 28672 = 50848 B.
// R0-R6 evidence trail: bank-conflict counter partially structural (R4: 5.1e7->3.7e7);
// barrier count not the bottleneck (R3); T14 prefetch +10% (R4); k4 fusion free (R6).
__global__ __launch_bounds__(256, 2) void k5_main(const float* __restrict__ x, const float* __restrict__ xc,
                                                  const int* __restrict__ mask, const float* __restrict__ stats,
                                                  float* __restrict__ ssum) {
    __shared__ __align__(16) float f0in[42 * 44];
    __shared__ __align__(16) float f1in[42 * 44];
    __shared__ __align__(16) float f2in[42 * 44];
    __shared__ __align__(16) float vb5[32 * VPITCH];
    const int t = threadIdx.x;
    const int b = blockIdx.z;
    const int y0 = blockIdx.y * 32, x0 = blockIdx.x * 32;
    // gauss weights as named scalars (same numerics as the original gauss11)
    const double e0 = exp(-25.0 / 4.5), e1 = exp(-16.0 / 4.5), e2d = exp(-9.0 / 4.5),
                 e3 = exp(-4.0 / 4.5), e4 = exp(-1.0 / 4.5);
    const double sg = 1.0 + 2.0 * (e0 + e1 + e2d + e3 + e4);
    const float G0 = (float)(e0 / sg), G1 = (float)(e1 / sg), G2 = (float)(e2d / sg),
                G3 = (float)(e3 / sg), G4 = (float)(e4 / sg), G5 = (float)(1.0 / sg);
    const float G6 = G4, G7 = G3, G8 = G2, G9 = G1, G10 = G0;
    const float gwA[11] = { G0, G1, G2, G3, G4, G5, G6, G7, G8, G9, G10 };
    // per-(b,i) normalization constants
    const float nst = stats[b * 8 + 0];
    const float s1a = stats[b * 8 + 1], s2a = stats[b * 8 + 4];
    const float s1b = stats[b * 8 + 2], s2b = stats[b * 8 + 5];
    const float s1c = stats[b * 8 + 3], s2c = stats[b * 8 + 6];
    const float mean0 = s1a / nst, rstd0 = rsqrtf((s2a - s1a * s1a / nst) / (nst - 1.0f));
    const float mean1 = s1b / nst, rstd1 = rsqrtf((s2b - s1b * s1b / nst) / (nst - 1.0f));
    const float mean2 = s1c / nst, rstd2 = rsqrtf((s2c - s1c * s1c / nst) / (nst - 1.0f));
    // stage normalized xf tiles (once per block)
    for (int q = t; q < 42 * 11; q += 256) {
        int row = q / 11, cg = q % 11;
        int gr = min(y0 + row, 255), gc = min(x0 + cg * 4, 252);
        int go = gr * 256 + gc;
        int lo = row * 44 + cg * 4;
        int4 mv = *(const int4*)(mask + (size_t)b * HWc + go);
        float m0 = (float)mv.x, m1 = (float)mv.y, m2 = (float)mv.z, m3 = (float)mv.w;
        float4 v0 = *(const float4*)(xc + (size_t)(b * 3 + 0) * HWc + go);
        v0.x = (v0.x - mean0) * rstd0 * m0; v0.y = (v0.y - mean0) * rstd0 * m1;
        v0.z = (v0.z - mean0) * rstd0 * m2; v0.w = (v0.w - mean0) * rstd0 * m3;
        *(float4*)&f0in[lo] = v0;
        float4 v1 = *(const float4*)(xc + (size_t)(b * 3 + 1) * HWc + go);
        v1.x = (v1.x - mean1) * rstd1 * m0; v1.y = (v1.y - mean1) * rstd1 * m1;
        v1.z = (v1.z - mean1) * rstd1 * m2; v1.w = (v1.w - mean1) * rstd1 * m3;
        *(float4*)&f1in[lo] = v1;
        float4 v2 = *(const float4*)(xc + (size_t)(b * 3 + 2) * HWc + go);
        v2.x = (v2.x - mean2) * rstd2 * m0; v2.y = (v2.y - mean2) * rstd2 * m1;
        v2.z = (v2.z - mean2) * rstd2 * m2; v2.w = (v2.w - mean2) * rstd2 * m3;
        *(float4*)&f2in[lo] = v2;
    }
    // per-thread c-independent eval constants
    const int erow = t >> 3, ecg = t & 7;
    const int oy = y0 + erow;
    const int ox0 = x0 + ecg * 4;
    DECLJ(0) DECLJ(1) DECLJ(2) DECLJ(3)
    const float* xb = x + (size_t)b * Cn * HWc;
    const int vrg = t / 11, vcg = t % 11, vcolo = vcg * 4;
    const int gcb = min(x0 + vcolo, 252);
    const bool vact = (t < 176);
    float4 xv0, xv1, xv2, xv3, xv4, xv5, xv6, xv7, xv8, xv9, xv10, xv11;

    __syncthreads();           // f-tiles staged
    // fused k4: 3 planes of {vert blur -> vb5 -> horiz blur -> M/S regs}
    VERTF(f0in);
    __syncthreads();
    HORIZF(0);
    __syncthreads();           // vb5 consumed
    VERTF(f1in);
    __syncthreads();
    HORIZF(1);
    __syncthreads();
    VERTF(f2in);
    __syncthreads();
    XLOAD(0);                  // prefetch channel 0; in flight across HORIZF(2)+bar
    HORIZF(2);
    __syncthreads();           // vb5 consumed; channel loop may overwrite
#pragma unroll 1
    for (int c = 0; c < Cn; ++c) {
        VCOMP(vb5);            // consume xv(c); vert compute + LDS write
        XLOAD(c + 1);          // issue next channel's loads (clamped at c=63: redundant, L2-hot)
        __syncthreads();       // vb5 written
        HORIZ(c, vb5);         // ~1200+ VALU cycles/SIMD hide the in-flight loads
        __syncthreads();       // vb5 consumed before next VCOMP overwrites
    }
}

// K6: normalize ssim sums -> ssim_info output; conv3 over C + MLP head -> h output
__global__ __launch_bounds__(512) void k6_head(const float* __restrict__ ssum, const float* __restrict__ cw,
                                               const float* __restrict__ w1, const float* __restrict__ b1,
                                               const float* __restrict__ w2, const float* __restrict__ b2,
                                               float* __restrict__ out) {
    __shared__ float si[1536];
    __shared__ float h0[512];
    __shared__ float h1[512];
    const int t = threadIdx.x;
    const float inv = 1.0f / (float)HPWPc;
    for (int idx = t; idx < 1536; idx += 512) {
        float v = ssum[idx] * inv;
        si[idx] = v;
        out[512 + idx] = v;
    }
    __syncthreads();
    const int b = t >> 6, y = t & 63;
    float acc = 0.f;
#pragma unroll
    for (int i = 0; i < 3; ++i) {
#pragma unroll
        for (int kh = 0; kh < 3; ++kh) {
            int yy = y + kh - 1;
            if (yy >= 0 && yy < 64) acc = fmaf(si[(b * 3 + i) * 64 + yy], cw[i * 3 + kh], acc);
        }
    }
    h0[t] = fmaxf(acc, 0.f);
    __syncthreads();
    float a1 = b1[y];
    for (int c = 0; c < 64; ++c) a1 = fmaf(h0[(b << 6) + c], w1[(y << 6) + c], a1);
    h1[t] = fmaxf(a1, 0.f);
    __syncthreads();
    float a2 = b2[y];
    for (int c = 0; c < 64; ++c) a2 = fmaf(h1[(b << 6) + c], w2[(y << 6) + c], a2);
    out[t] = 1.f / (1.f + expf(-a2));
}

extern "C" void kernel_launch(void* const* d_in, const int* in_sizes, int n_in,
                              void* d_out, int out_size, void* d_ws, size_t ws_size,
                              hipStream_t stream) {
    const float* x      = (const float*)d_in[0];
    const int*   mask   = (const int*)d_in[1];
    const float* conv_w = (const float*)d_in[2];
    const float* w1     = (const float*)d_in[3];
    const float* b1     = (const float*)d_in[4];
    const float* w2     = (const float*)d_in[5];
    const float* b2     = (const float*)d_in[6];
    float* out = (float*)d_out;

    float* wsf   = (float*)d_ws;
    float* stats = wsf;                       // 64 floats (8 b x 8 slots)
    float* ssum  = wsf + 64;                  // 1536 floats
    float* xcf   = wsf + 1600;                // 8*3*65536 raw xc (max/mean/min)

    hipMemsetAsync(d_ws, 0, 6400, stream);  // stats + ssum accumulators

    k1_stats<<<dim3(64, 8), 256, 0, stream>>>(x, mask, xcf, stats);
    k5_main<<<dim3(8, 8, 8), 256, 0, stream>>>(x, xcf, mask, stats, ssum);
    k6_head<<<1, 512, 0, stream>>>(ssum, conv_w, w1, b1, w2, b2, out);
}